// Round 1
// baseline (5693.949 us; speedup 1.0000x reference)
//
#include <hip/hip_runtime.h>
#include <math.h>

// Problem constants (B,C,H,W = 16,512,64,64)
#define BATCH 16
#define CH    512
#define CH2   256
#define CH4   128
#define HH    64
#define WW    64
#define HWSZ  4096
#define EPSV  1e-5f

// ---------------------------------------------------------------------------
// prep: fold BN params.  s = g*rsqrt(v+eps);  t = (conv_bias - m)*s + b
// ---------------------------------------------------------------------------
__global__ void prep_params(
    const float* __restrict__ q1_b, const float* __restrict__ g1, const float* __restrict__ b1,
    const float* __restrict__ m1, const float* __restrict__ v1,
    const float* __restrict__ q2_b, const float* __restrict__ g2, const float* __restrict__ b2,
    const float* __restrict__ m2, const float* __restrict__ v2,
    const float* __restrict__ fus_b, const float* __restrict__ g3, const float* __restrict__ b3,
    const float* __restrict__ m3, const float* __restrict__ v3,
    float* __restrict__ s1, float* __restrict__ t1,
    float* __restrict__ s2, float* __restrict__ t2,
    float* __restrict__ s3, float* __restrict__ t3)
{
    int i = threadIdx.x;
    if (i < CH2) { float s = g1[i] * rsqrtf(v1[i] + EPSV); s1[i] = s; t1[i] = (q1_b[i] - m1[i]) * s + b1[i]; }
    if (i < CH4) { float s = g2[i] * rsqrtf(v2[i] + EPSV); s2[i] = s; t2[i] = (q2_b[i] - m2[i]) * s + b2[i]; }
    if (i < CH)  { float s = g3[i] * rsqrtf(v3[i] + EPSV); s3[i] = s; t3[i] = (fus_b[i] - m3[i]) * s + b3[i]; }
}

// ---------------------------------------------------------------------------
// tiny transposes
// ---------------------------------------------------------------------------
__global__ void transpose_p1(const float* __restrict__ p1w, float* __restrict__ p1T)
{
    int c = blockIdx.x;      // 256
    int o = threadIdx.x;     // 256
    p1T[c * CH2 + o] = p1w[o * CH2 + c];
}

// fus_w [O=512][C=512][3][3] -> wT [(c*9+rs)*512 + o]
__global__ void transpose_w(const float* __restrict__ fw, float* __restrict__ wT)
{
    int crs = blockIdx.x;    // 0..4607
    int o   = threadIdx.x;   // 0..511
    wT[(long)crs * CH + o] = fw[(long)o * (CH * 9) + crs];
}

// ---------------------------------------------------------------------------
// Tiled fp32 GEMM  C[m,n] = epi( sum_k A[m,k]*B[k,n] )
// tile 64x64, BK=16, 256 threads, 4x4 micro-tile.
// EPI: 0 = relu(acc*scale[m]+shift[m])
//      1 = gamma[0]*acc + X[b][m,n]
//      2 = acc + shift[n]
//      3 = acc
// ---------------------------------------------------------------------------
template<int EPI>
__global__ __launch_bounds__(256)
void gemm_ab(const float* __restrict__ A, const float* __restrict__ Bm,
             float* __restrict__ Cm,
             int M, int N, int K,
             long sA, long sB, long sC,
             const float* __restrict__ scale, const float* __restrict__ shift,
             const float* __restrict__ X, long sX, const float* __restrict__ gamma)
{
    __shared__ float As[16][68];
    __shared__ float Bs[16][68];

    const int b   = blockIdx.z;
    const float* Ab = A  + (long)b * sA;
    const float* Bb = Bm + (long)b * sB;
    float*       Cb = Cm + (long)b * sC;

    const int m0 = blockIdx.y * 64;
    const int n0 = blockIdx.x * 64;
    const int tid = threadIdx.x;
    const int tx = tid & 15;        // n group
    const int ty = tid >> 4;        // m group

    const int a_m = tid >> 2;            // 0..63
    const int a_k = (tid & 3) * 4;       // 0..12
    const int b_k = tid >> 4;            // 0..15
    const int b_n = (tid & 15) * 4;      // 0..60

    float acc[4][4] = {};

    for (int k0 = 0; k0 < K; k0 += 16) {
        float4 av = *(const float4*)&Ab[(long)(m0 + a_m) * K + k0 + a_k];
        float4 bv = *(const float4*)&Bb[(long)(k0 + b_k) * N + n0 + b_n];
        As[a_k + 0][a_m] = av.x;
        As[a_k + 1][a_m] = av.y;
        As[a_k + 2][a_m] = av.z;
        As[a_k + 3][a_m] = av.w;
        *(float4*)&Bs[b_k][b_n] = bv;
        __syncthreads();
        #pragma unroll
        for (int k = 0; k < 16; ++k) {
            float4 a4 = *(const float4*)&As[k][ty * 4];
            float4 b4 = *(const float4*)&Bs[k][tx * 4];
            float ar[4] = {a4.x, a4.y, a4.z, a4.w};
            float br[4] = {b4.x, b4.y, b4.z, b4.w};
            #pragma unroll
            for (int i = 0; i < 4; ++i)
                #pragma unroll
                for (int j = 0; j < 4; ++j)
                    acc[i][j] += ar[i] * br[j];
        }
        __syncthreads();
    }

    #pragma unroll
    for (int i = 0; i < 4; ++i) {
        const int m = m0 + ty * 4 + i;
        float v[4];
        #pragma unroll
        for (int j = 0; j < 4; ++j) {
            const int n = n0 + tx * 4 + j;
            float val = acc[i][j];
            if constexpr (EPI == 0) { val = fmaxf(val * scale[m] + shift[m], 0.0f); }
            if constexpr (EPI == 1) { val = gamma[0] * val + X[(long)b * sX + (long)m * N + n]; }
            if constexpr (EPI == 2) { val = val + shift[n]; }
            v[j] = val;
        }
        *(float4*)&Cb[(long)m * N + n0 + tx * 4] = make_float4(v[0], v[1], v[2], v[3]);
    }
}

// ---------------------------------------------------------------------------
// Tiled fp32 GEMM  C[m,n] = epi( sum_k A[m,k]*B[n,k] )   (A.B^T, k contiguous)
// EPI: 0 = acc ; 1 = acc + shift[m]
// ---------------------------------------------------------------------------
template<int EPI>
__global__ __launch_bounds__(256)
void gemm_abT(const float* __restrict__ A, const float* __restrict__ Bm,
              float* __restrict__ Cm,
              int M, int N, int K,
              long sA, long sB, long sC,
              const float* __restrict__ shift)
{
    __shared__ float As[16][68];
    __shared__ float Bs[16][68];

    const int b   = blockIdx.z;
    const float* Ab = A  + (long)b * sA;
    const float* Bb = Bm + (long)b * sB;
    float*       Cb = Cm + (long)b * sC;

    const int m0 = blockIdx.y * 64;
    const int n0 = blockIdx.x * 64;
    const int tid = threadIdx.x;
    const int tx = tid & 15;
    const int ty = tid >> 4;

    const int r  = tid >> 2;        // 0..63 row in tile
    const int kq = (tid & 3) * 4;   // 0..12

    float acc[4][4] = {};

    for (int k0 = 0; k0 < K; k0 += 16) {
        float4 av = *(const float4*)&Ab[(long)(m0 + r) * K + k0 + kq];
        float4 bv = *(const float4*)&Bb[(long)(n0 + r) * K + k0 + kq];
        As[kq + 0][r] = av.x; As[kq + 1][r] = av.y; As[kq + 2][r] = av.z; As[kq + 3][r] = av.w;
        Bs[kq + 0][r] = bv.x; Bs[kq + 1][r] = bv.y; Bs[kq + 2][r] = bv.z; Bs[kq + 3][r] = bv.w;
        __syncthreads();
        #pragma unroll
        for (int k = 0; k < 16; ++k) {
            float4 a4 = *(const float4*)&As[k][ty * 4];
            float4 b4 = *(const float4*)&Bs[k][tx * 4];
            float ar[4] = {a4.x, a4.y, a4.z, a4.w};
            float br[4] = {b4.x, b4.y, b4.z, b4.w};
            #pragma unroll
            for (int i = 0; i < 4; ++i)
                #pragma unroll
                for (int j = 0; j < 4; ++j)
                    acc[i][j] += ar[i] * br[j];
        }
        __syncthreads();
    }

    #pragma unroll
    for (int i = 0; i < 4; ++i) {
        const int m = m0 + ty * 4 + i;
        float v[4];
        #pragma unroll
        for (int j = 0; j < 4; ++j) {
            float val = acc[i][j];
            if constexpr (EPI == 1) { val = val + shift[m]; }
            v[j] = val;
        }
        *(float4*)&Cb[(long)m * N + n0 + tx * 4] = make_float4(v[0], v[1], v[2], v[3]);
    }
}

// ---------------------------------------------------------------------------
// softmax over rows of 128:  att = softmax(rowmax - e) == exp(rowmin-e)/sum
// ---------------------------------------------------------------------------
__global__ void softmax_rows(float* __restrict__ e)
{
    const int row  = blockIdx.x;      // B*512
    const int lane = threadIdx.x;     // 64
    float* p = e + (long)row * CH4;
    float a = p[lane];
    float c = p[lane + 64];
    float mn = fminf(a, c);
    #pragma unroll
    for (int off = 32; off; off >>= 1) mn = fminf(mn, __shfl_xor(mn, off));
    float ea = expf(mn - a);
    float ec = expf(mn - c);
    float s = ea + ec;
    #pragma unroll
    for (int off = 32; off; off >>= 1) s += __shfl_xor(s, off);
    float inv = 1.0f / s;
    p[lane]      = ea * inv;
    p[lane + 64] = ec * inv;
}

// ---------------------------------------------------------------------------
// 3x3 conv + BN + ReLU.  Block: 128 out-ch x one 64-px row. C chunked by 8.
// grid (64 rows, 16 batch, 4 oblk)  -> 1024 consecutive blocks share weights
// ---------------------------------------------------------------------------
__global__ __launch_bounds__(256)
void conv3_bn_relu(const float* __restrict__ pre, const float* __restrict__ wT,
                   const float* __restrict__ s3, const float* __restrict__ t3,
                   float* __restrict__ outp)
{
    const int h  = blockIdx.x;
    const int b  = blockIdx.y;
    const int ob = blockIdx.z;
    const int tid = threadIdx.x;
    const int tw = tid & 15;      // 4 w each
    const int to = tid >> 4;      // 8 o each

    __shared__ float wLds[72][128];     // [(cc*3+r)*3+s][oo]
    __shared__ float iLds[3][8][68];    // [r][cc][wi], 66 used

    float acc[8][4] = {};
    const float* preB = pre + (long)b * CH * HWSZ;

    for (int c0 = 0; c0 < CH; c0 += 8) {
        // ---- stage weights: wT[(c*9 + rs)*512 + o]; (c0+cc)*9+rs == c0*9 + t
        {
            const int oo = tid & 127;
            const int th = tid >> 7;                // 0/1
            const long basew = (long)c0 * 9 * CH + (long)ob * 128 + oo;
            #pragma unroll
            for (int t = 0; t < 72; t += 2) {
                wLds[t + th][oo] = wT[basew + (long)(t + th) * CH];
            }
        }
        // ---- stage input rows h-1..h+1, cols -1..64 (zero padded)
        for (int idx = tid; idx < 24 * 66; idx += 256) {
            const int rowi = idx / 66;
            const int wi   = idx - rowi * 66;
            const int rr   = rowi >> 3;
            const int cc   = rowi & 7;
            const int hr = h - 1 + rr;
            const int w  = wi - 1;
            float v = 0.0f;
            if ((unsigned)hr < 64u && (unsigned)w < 64u)
                v = preB[(long)(c0 + cc) * HWSZ + hr * WW + w];
            iLds[rr][cc][wi] = v;
        }
        __syncthreads();

        // ---- compute
        #pragma unroll
        for (int cc = 0; cc < 8; ++cc) {
            #pragma unroll
            for (int rr = 0; rr < 3; ++rr) {
                float4 i4 = *(const float4*)&iLds[rr][cc][tw * 4];
                float2 i2 = *(const float2*)&iLds[rr][cc][tw * 4 + 4];
                float iv[6] = {i4.x, i4.y, i4.z, i4.w, i2.x, i2.y};
                #pragma unroll
                for (int s = 0; s < 3; ++s) {
                    const int t = (cc * 3 + rr) * 3 + s;
                    float4 wa = *(const float4*)&wLds[t][to * 8];
                    float4 wb = *(const float4*)&wLds[t][to * 8 + 4];
                    float wr[8] = {wa.x, wa.y, wa.z, wa.w, wb.x, wb.y, wb.z, wb.w};
                    #pragma unroll
                    for (int i = 0; i < 8; ++i)
                        #pragma unroll
                        for (int j = 0; j < 4; ++j)
                            acc[i][j] += wr[i] * iv[j + s];
                }
            }
        }
        __syncthreads();
    }

    const int wbase = tw * 4;
    #pragma unroll
    for (int i = 0; i < 8; ++i) {
        const int o = ob * 128 + to * 8 + i;
        const float sc = s3[o];
        const float tt = t3[o];
        float4 v;
        v.x = fmaxf(acc[i][0] * sc + tt, 0.0f);
        v.y = fmaxf(acc[i][1] * sc + tt, 0.0f);
        v.z = fmaxf(acc[i][2] * sc + tt, 0.0f);
        v.w = fmaxf(acc[i][3] * sc + tt, 0.0f);
        *(float4*)&outp[((long)b * CH + o) * HWSZ + h * WW + wbase] = v;
    }
}

// ---------------------------------------------------------------------------
extern "C" void kernel_launch(void* const* d_in, const int* in_sizes, int n_in,
                              void* d_out, int out_size, void* d_ws, size_t ws_size,
                              hipStream_t stream)
{
    const float* x     = (const float*)d_in[0];
    const float* q1_w  = (const float*)d_in[1];
    const float* q1_b  = (const float*)d_in[2];
    const float* bn1_g = (const float*)d_in[3];
    const float* bn1_b = (const float*)d_in[4];
    const float* bn1_m = (const float*)d_in[5];
    const float* bn1_v = (const float*)d_in[6];
    const float* q2_w  = (const float*)d_in[7];
    const float* q2_b  = (const float*)d_in[8];
    const float* bn2_g = (const float*)d_in[9];
    const float* bn2_b = (const float*)d_in[10];
    const float* bn2_m = (const float*)d_in[11];
    const float* bn2_v = (const float*)d_in[12];
    const float* p1_w  = (const float*)d_in[13];
    const float* p1_b  = (const float*)d_in[14];
    const float* fus_w = (const float*)d_in[15];
    const float* fus_b = (const float*)d_in[16];
    const float* bn3_g = (const float*)d_in[17];
    const float* bn3_b = (const float*)d_in[18];
    const float* bn3_m = (const float*)d_in[19];
    const float* bn3_v = (const float*)d_in[20];
    const float* gamma = (const float*)d_in[21];
    float* outp = (float*)d_out;

    // ---- workspace carve (floats) with aliasing: pre overlaps py1/e1T/e2
    float* ws = (float*)d_ws;
    size_t off = 0;
    float* py2    = ws + off; off += (size_t)BATCH * CH4 * HWSZ;   // 8,388,608
    float* e1pt   = ws + off; off += (size_t)BATCH * CH  * CH2;    // 2,097,152
    float* e2p    = ws + off; off += (size_t)BATCH * CH2 * CH4;    //   524,288
    float* energy = ws + off; off += (size_t)BATCH * CH  * CH4;    // 1,048,576
    float* p1T    = ws + off; off += (size_t)CH2 * CH2;            //    65,536
    float* wT     = ws + off; off += (size_t)CH * CH * 9;          // 2,359,296
    float* s1 = ws + off; off += CH2;
    float* t1 = ws + off; off += CH2;
    float* s2 = ws + off; off += CH4;
    float* t2 = ws + off; off += CH4;
    float* s3 = ws + off; off += CH;
    float* t3 = ws + off; off += CH;
    // overlapping region:
    float* py1 = ws + off;                       // 16,777,216 (dead after e2)
    float* e1T = py1 + (size_t)BATCH * CH2 * HWSZ;   // 2,097,152 (dead after e1pt)
    float* e2  = e1T + (size_t)BATCH * CH  * CH2;    //   524,288 (dead after e2p)
    float* pre = py1;                            // 33,554,432 — written only after all of the above are dead

    const long sHW_C  = (long)CH  * HWSZ;
    const long sHW_C2 = (long)CH2 * HWSZ;
    const long sHW_C4 = (long)CH4 * HWSZ;

    prep_params<<<1, 512, 0, stream>>>(q1_b, bn1_g, bn1_b, bn1_m, bn1_v,
                                       q2_b, bn2_g, bn2_b, bn2_m, bn2_v,
                                       fus_b, bn3_g, bn3_b, bn3_m, bn3_v,
                                       s1, t1, s2, t2, s3, t3);
    transpose_p1<<<CH2, CH2, 0, stream>>>(p1_w, p1T);
    transpose_w<<<CH * 9, CH, 0, stream>>>(fus_w, wT);

    // py1 = relu(bn1(q1_w @ x))           [256 x 4096] per batch, K=512
    gemm_ab<0><<<dim3(64, 4, BATCH), 256, 0, stream>>>(
        q1_w, x, py1, CH2, HWSZ, CH, 0, sHW_C, sHW_C2, s1, t1, nullptr, 0, nullptr);

    // py2 = relu(bn2(q2_w @ py1))         [128 x 4096] per batch, K=256
    gemm_ab<0><<<dim3(64, 2, BATCH), 256, 0, stream>>>(
        q2_w, py1, py2, CH4, HWSZ, CH2, 0, sHW_C2, sHW_C4, s2, t2, nullptr, 0, nullptr);

    // e1T[d,c] = sum_n x[d,n]*py1[c,n]    [512 x 256] per batch, K=4096
    gemm_abT<0><<<dim3(4, 8, BATCH), 256, 0, stream>>>(
        x, py1, e1T, CH, CH2, HWSZ, sHW_C, sHW_C2, (long)CH * CH2, nullptr);

    // e2[c,d] = sum_n py2[c,n]*py1[d,n]   [128 x 256] per batch, K=4096
    gemm_abT<0><<<dim3(4, 2, BATCH), 256, 0, stream>>>(
        py2, py1, e2, CH4, CH2, HWSZ, sHW_C4, sHW_C2, (long)CH4 * CH2, nullptr);

    // e2p[o,c] = sum_d p1_w[o,d]*e2[c,d] + p1_b[o]   [256 x 128], K=256
    gemm_abT<1><<<dim3(2, 4, BATCH), 256, 0, stream>>>(
        p1_w, e2, e2p, CH2, CH4, CH2, 0, (long)CH4 * CH2, (long)CH2 * CH4, p1_b);

    // e1pt[d,o] = sum_c e1T[d,c]*p1T[c,o] + p1_b[o]  [512 x 256], K=256
    gemm_ab<2><<<dim3(4, 8, BATCH), 256, 0, stream>>>(
        e1T, p1T, e1pt, CH, CH2, CH2, (long)CH * CH2, 0, (long)CH * CH2,
        nullptr, p1_b, nullptr, 0, nullptr);

    // energy[c,d] = sum_e e1pt[c,e]*e2p[e,d]         [512 x 128], K=256
    gemm_ab<3><<<dim3(2, 8, BATCH), 256, 0, stream>>>(
        e1pt, e2p, energy, CH, CH4, CH2, (long)CH * CH2, (long)CH2 * CH4, (long)CH * CH4,
        nullptr, nullptr, nullptr, 0, nullptr);

    // attention in-place
    softmax_rows<<<BATCH * CH, 64, 0, stream>>>(energy);

    // pre = gamma * (att @ py2) + x                  [512 x 4096], K=128
    gemm_ab<1><<<dim3(64, 8, BATCH), 256, 0, stream>>>(
        energy, py2, pre, CH, HWSZ, CH4, (long)CH * CH4, sHW_C4, sHW_C,
        nullptr, nullptr, x, sHW_C, gamma);

    // out = relu(bn3(conv3x3(pre) + fus_b))
    conv3_bn_relu<<<dim3(HH, BATCH, 4), 256, 0, stream>>>(pre, wT, s3, t3, outp);
}

// Round 2
// 1462.231 us; speedup vs baseline: 3.8940x; 3.8940x over previous
//
#include <hip/hip_runtime.h>
#include <math.h>

// Problem constants (B,C,H,W = 16,512,64,64)
#define BATCH 16
#define CH    512
#define CH2   256
#define CH4   128
#define HH    64
#define WW    64
#define HWSZ  4096
#define EPSV  1e-5f
// padded fp16 conv-input layout [b][h'=0..65][w'=0..65][c=0..511]
#define HP 66
#define WP 66

typedef _Float16 f16x8 __attribute__((ext_vector_type(8)));
typedef float    f32x4 __attribute__((ext_vector_type(4)));

#define GLOBAL_AS __attribute__((address_space(1)))
#define LDS_AS    __attribute__((address_space(3)))

__device__ __forceinline__ void gload16(const void* g, void* l) {
    __builtin_amdgcn_global_load_lds((const GLOBAL_AS unsigned int*)g,
                                     (LDS_AS unsigned int*)l, 16, 0, 0);
}

// ---------------------------------------------------------------------------
// prep: fold BN params.  s = g*rsqrt(v+eps);  t = (conv_bias - m)*s + b
// ---------------------------------------------------------------------------
__global__ void prep_params(
    const float* __restrict__ q1_b, const float* __restrict__ g1, const float* __restrict__ b1,
    const float* __restrict__ m1, const float* __restrict__ v1,
    const float* __restrict__ q2_b, const float* __restrict__ g2, const float* __restrict__ b2,
    const float* __restrict__ m2, const float* __restrict__ v2,
    const float* __restrict__ fus_b, const float* __restrict__ g3, const float* __restrict__ b3,
    const float* __restrict__ m3, const float* __restrict__ v3,
    float* __restrict__ s1, float* __restrict__ t1,
    float* __restrict__ s2, float* __restrict__ t2,
    float* __restrict__ s3, float* __restrict__ t3)
{
    int i = threadIdx.x;
    if (i < CH2) { float s = g1[i] * rsqrtf(v1[i] + EPSV); s1[i] = s; t1[i] = (q1_b[i] - m1[i]) * s + b1[i]; }
    if (i < CH4) { float s = g2[i] * rsqrtf(v2[i] + EPSV); s2[i] = s; t2[i] = (q2_b[i] - m2[i]) * s + b2[i]; }
    if (i < CH)  { float s = g3[i] * rsqrtf(v3[i] + EPSV); s3[i] = s; t3[i] = (fus_b[i] - m3[i]) * s + b3[i]; }
}

__global__ void transpose_p1(const float* __restrict__ p1w, float* __restrict__ p1T)
{
    int c = blockIdx.x;      // 256
    int o = threadIdx.x;     // 256
    p1T[c * CH2 + o] = p1w[o * CH2 + c];
}

// fus_w [o][c][3][3] fp32 -> wH [t][o][c] fp16
__global__ void repack_w(const float* __restrict__ fw, ushort* __restrict__ wH)
{
    int o = blockIdx.x;           // 512
    int c = threadIdx.x;          // 512
    const float* src = fw + ((size_t)o * CH + c) * 9;
    #pragma unroll
    for (int t = 0; t < 9; ++t) {
        _Float16 h = (_Float16)src[t];
        wH[((size_t)t * CH + o) * CH + c] = *(ushort*)&h;
    }
}

__global__ void zero_buf(uint4* __restrict__ p, int n)
{
    const uint4 z = make_uint4(0u, 0u, 0u, 0u);
    for (int i = blockIdx.x * blockDim.x + threadIdx.x; i < n; i += gridDim.x * blockDim.x)
        p[i] = z;
}

// ---------------------------------------------------------------------------
// Tiled fp32 GEMM  C[m,n] = epi( sum_k A[m,k]*B[k,n] )
// tile 64x64, BK=16, 256 threads, 4x4 micro-tile.
// EPI: 0 = relu(acc*scale[m]+shift[m]) ; 2 = acc + shift[n] ; 3 = acc
//      4 = fp16(gamma[0]*acc + X) written into padded pixel-major preH
// ---------------------------------------------------------------------------
template<int EPI>
__global__ __launch_bounds__(256)
void gemm_ab(const float* __restrict__ A, const float* __restrict__ Bm,
             float* __restrict__ Cm,
             int M, int N, int K,
             long sA, long sB, long sC,
             const float* __restrict__ scale, const float* __restrict__ shift,
             const float* __restrict__ X, long sX, const float* __restrict__ gamma,
             ushort* __restrict__ PH)
{
    __shared__ float As[16][68];
    __shared__ float Bs[16][68];

    const int b   = blockIdx.z;
    const float* Ab = A  + (long)b * sA;
    const float* Bb = Bm + (long)b * sB;

    const int m0 = blockIdx.y * 64;
    const int n0 = blockIdx.x * 64;
    const int tid = threadIdx.x;
    const int tx = tid & 15;        // n group
    const int ty = tid >> 4;        // m group

    const int a_m = tid >> 2;            // 0..63
    const int a_k = (tid & 3) * 4;       // 0..12
    const int b_k = tid >> 4;            // 0..15
    const int b_n = (tid & 15) * 4;      // 0..60

    float acc[4][4] = {};

    for (int k0 = 0; k0 < K; k0 += 16) {
        float4 av = *(const float4*)&Ab[(long)(m0 + a_m) * K + k0 + a_k];
        float4 bv = *(const float4*)&Bb[(long)(k0 + b_k) * N + n0 + b_n];
        As[a_k + 0][a_m] = av.x;
        As[a_k + 1][a_m] = av.y;
        As[a_k + 2][a_m] = av.z;
        As[a_k + 3][a_m] = av.w;
        *(float4*)&Bs[b_k][b_n] = bv;
        __syncthreads();
        #pragma unroll
        for (int k = 0; k < 16; ++k) {
            float4 a4 = *(const float4*)&As[k][ty * 4];
            float4 b4 = *(const float4*)&Bs[k][tx * 4];
            float ar[4] = {a4.x, a4.y, a4.z, a4.w};
            float br[4] = {b4.x, b4.y, b4.z, b4.w};
            #pragma unroll
            for (int i = 0; i < 4; ++i)
                #pragma unroll
                for (int j = 0; j < 4; ++j)
                    acc[i][j] += ar[i] * br[j];
        }
        __syncthreads();
    }

    if constexpr (EPI == 4) {
        // write fp16(gamma*acc + x) into padded pixel-major preH[b][h+1][w+1][ch]
        const int h = blockIdx.x;            // grid.x == 64 == rows, N == 4096
        const float g = gamma[0];
        #pragma unroll
        for (int j = 0; j < 4; ++j) {
            const int n = n0 + tx * 4 + j;
            const int w = n & 63;
            ushort4 pk;
            ushort* pp = (ushort*)&pk;
            #pragma unroll
            for (int i = 0; i < 4; ++i) {
                const int m = m0 + ty * 4 + i;
                float val = g * acc[i][j] + X[(long)b * sX + (long)m * N + n];
                _Float16 hv = (_Float16)val;
                pp[i] = *(ushort*)&hv;
            }
            *(ushort4*)&PH[((size_t)(b * HP + h + 1) * WP + (w + 1)) * CH + m0 + ty * 4] = pk;
        }
        return;
    }

    float* Cb = Cm + (long)b * sC;
    #pragma unroll
    for (int i = 0; i < 4; ++i) {
        const int m = m0 + ty * 4 + i;
        float v[4];
        #pragma unroll
        for (int j = 0; j < 4; ++j) {
            float val = acc[i][j];
            if constexpr (EPI == 0) { val = fmaxf(val * scale[m] + shift[m], 0.0f); }
            if constexpr (EPI == 2) { val = val + shift[n0 + tx * 4 + j]; }
            v[j] = val;
        }
        *(float4*)&Cb[(long)m * N + n0 + tx * 4] = make_float4(v[0], v[1], v[2], v[3]);
    }
}

// ---------------------------------------------------------------------------
// Tiled fp32 GEMM  C[m,n] = epi( sum_k A[m,k]*B[n,k] )   (A.B^T, k contiguous)
// EPI: 0 = acc ; 1 = acc + shift[m]
// ---------------------------------------------------------------------------
template<int EPI>
__global__ __launch_bounds__(256)
void gemm_abT(const float* __restrict__ A, const float* __restrict__ Bm,
              float* __restrict__ Cm,
              int M, int N, int K,
              long sA, long sB, long sC,
              const float* __restrict__ shift)
{
    __shared__ float As[16][68];
    __shared__ float Bs[16][68];

    const int b   = blockIdx.z;
    const float* Ab = A  + (long)b * sA;
    const float* Bb = Bm + (long)b * sB;
    float*       Cb = Cm + (long)b * sC;

    const int m0 = blockIdx.y * 64;
    const int n0 = blockIdx.x * 64;
    const int tid = threadIdx.x;
    const int tx = tid & 15;
    const int ty = tid >> 4;

    const int r  = tid >> 2;        // 0..63 row in tile
    const int kq = (tid & 3) * 4;   // 0..12

    float acc[4][4] = {};

    for (int k0 = 0; k0 < K; k0 += 16) {
        float4 av = *(const float4*)&Ab[(long)(m0 + r) * K + k0 + kq];
        float4 bv = *(const float4*)&Bb[(long)(n0 + r) * K + k0 + kq];
        As[kq + 0][r] = av.x; As[kq + 1][r] = av.y; As[kq + 2][r] = av.z; As[kq + 3][r] = av.w;
        Bs[kq + 0][r] = bv.x; Bs[kq + 1][r] = bv.y; Bs[kq + 2][r] = bv.z; Bs[kq + 3][r] = bv.w;
        __syncthreads();
        #pragma unroll
        for (int k = 0; k < 16; ++k) {
            float4 a4 = *(const float4*)&As[k][ty * 4];
            float4 b4 = *(const float4*)&Bs[k][tx * 4];
            float ar[4] = {a4.x, a4.y, a4.z, a4.w};
            float br[4] = {b4.x, b4.y, b4.z, b4.w};
            #pragma unroll
            for (int i = 0; i < 4; ++i)
                #pragma unroll
                for (int j = 0; j < 4; ++j)
                    acc[i][j] += ar[i] * br[j];
        }
        __syncthreads();
    }

    #pragma unroll
    for (int i = 0; i < 4; ++i) {
        const int m = m0 + ty * 4 + i;
        float v[4];
        #pragma unroll
        for (int j = 0; j < 4; ++j) {
            float val = acc[i][j];
            if constexpr (EPI == 1) { val = val + shift[m]; }
            v[j] = val;
        }
        *(float4*)&Cb[(long)m * N + n0 + tx * 4] = make_float4(v[0], v[1], v[2], v[3]);
    }
}

// ---------------------------------------------------------------------------
// softmax over rows of 128:  att = softmax(rowmax - e) == exp(rowmin-e)/sum
// ---------------------------------------------------------------------------
__global__ void softmax_rows(float* __restrict__ e)
{
    const int row  = blockIdx.x;      // B*512
    const int lane = threadIdx.x;     // 64
    float* p = e + (long)row * CH4;
    float a = p[lane];
    float c = p[lane + 64];
    float mn = fminf(a, c);
    #pragma unroll
    for (int off = 32; off; off >>= 1) mn = fminf(mn, __shfl_xor(mn, off));
    float ea = expf(mn - a);
    float ec = expf(mn - c);
    float s = ea + ec;
    #pragma unroll
    for (int off = 32; off; off >>= 1) s += __shfl_xor(s, off);
    float inv = 1.0f / s;
    p[lane]      = ea * inv;
    p[lane + 64] = ec * inv;
}

// ---------------------------------------------------------------------------
// 3x3 conv + BN + ReLU via fp16 MFMA implicit GEMM (m97 structure).
// M = 512 (o), N = pixels, K = 9 taps x 512 c.  Tile 128o x 128px, BK=32.
// preH: padded pixel-major [b][h'][w'][c] fp16;  wH: [t][o][c] fp16.
// Block: 256 thr = 4 waves (2m x 2n quadrants of 64).  Grid 2048, XCD-swizzled.
// ---------------------------------------------------------------------------
__global__ __launch_bounds__(256)
void conv3_mfma(const ushort* __restrict__ preH, const ushort* __restrict__ wH,
                const float* __restrict__ s3, const float* __restrict__ t3,
                float* __restrict__ outp)
{
    __shared__ alignas(16) ushort As[4096];  // [128 o][32 c]
    __shared__ alignas(16) ushort Bs[4096];  // [128 px][32 c]

    // logical id: ob-major then pixel-tile; chunked XCD swizzle (2048 = 8*256)
    const int bid = blockIdx.x;
    const int lin = (bid & 7) * 256 + (bid >> 3);
    const int ob  = lin >> 9;          // 0..3   (128 o each)
    const int pt  = lin & 511;         // 0..511 (16 b x 32 row-pairs)
    const int b   = pt >> 5;
    const int h0  = (pt & 31) * 2;     // output rows h0, h0+1
    const int o0  = ob * 128;

    const int tid  = threadIdx.x;
    const int lane = tid & 63;
    const int wv   = tid >> 6;
    const int wm   = wv >> 1;
    const int wn   = wv & 1;

    // staging: each wave issues LDS KB-parts {2wv, 2wv+1} for A and B
    const int cpart = (lane & 3) * 8;
    const int prow  = lane >> 2;                 // 0..15
    const int pA0 = wv * 2, pA1 = pA0 + 1;
    const size_t aBase0 = (size_t)(o0 + pA0 * 16 + prow) * CH + cpart;
    const size_t aBase1 = (size_t)(o0 + pA1 * 16 + prow) * CH + cpart;
    const int P0 = pA0 * 16 + prow, P1 = pA1 * 16 + prow;
    const size_t bBase0 = ((size_t)(b * HP + h0 + (P0 >> 6)) * WP + (P0 & 63)) * CH + cpart;
    const size_t bBase1 = ((size_t)(b * HP + h0 + (P1 >> 6)) * WP + (P1 & 63)) * CH + cpart;
    ushort* AsW = &As[(size_t)wv * 1024];
    ushort* BsW = &Bs[(size_t)wv * 1024];

    // fragment LDS offsets (ushort units)
    const int fr = lane & 15, fg = lane >> 4;
    const int aOff = (wm * 64 + fr) * 32 + fg * 8;
    const int bOff = (wn * 64 + fr) * 32 + fg * 8;

    f32x4 acc[4][4];
    const f32x4 vzero = {0.f, 0.f, 0.f, 0.f};
    #pragma unroll
    for (int i = 0; i < 4; ++i)
        #pragma unroll
        for (int j = 0; j < 4; ++j) acc[i][j] = vzero;

    for (int t = 0; t < 9; ++t) {
        const int r = t / 3, s = t - r * 3;
        const size_t tOffA = (size_t)t * CH * CH;
        const size_t tOffB = (size_t)(r * WP + s) * CH;
        for (int c0 = 0; c0 < CH; c0 += 32) {
            gload16(wH   + tOffA + aBase0 + c0, AsW);
            gload16(wH   + tOffA + aBase1 + c0, AsW + 512);
            gload16(preH + tOffB + bBase0 + c0, BsW);
            gload16(preH + tOffB + bBase1 + c0, BsW + 512);
            __syncthreads();

            f16x8 aF[4], bF[4];
            #pragma unroll
            for (int mi = 0; mi < 4; ++mi) aF[mi] = *(const f16x8*)&As[aOff + mi * 512];
            #pragma unroll
            for (int ni = 0; ni < 4; ++ni) bF[ni] = *(const f16x8*)&Bs[bOff + ni * 512];
            #pragma unroll
            for (int mi = 0; mi < 4; ++mi)
                #pragma unroll
                for (int ni = 0; ni < 4; ++ni)
                    acc[mi][ni] = __builtin_amdgcn_mfma_f32_16x16x32_f16(aF[mi], bF[ni], acc[mi][ni], 0, 0, 0);
            __syncthreads();
        }
    }

    // epilogue: D row(o) = (lane>>4)*4+reg (+16*mi+64*wm), col(px) = lane&15 (+16*ni+64*wn)
    #pragma unroll
    for (int mi = 0; mi < 4; ++mi) {
        #pragma unroll
        for (int reg = 0; reg < 4; ++reg) {
            const int o = o0 + wm * 64 + mi * 16 + fg * 4 + reg;
            const float sc = s3[o], tt = t3[o];
            #pragma unroll
            for (int ni = 0; ni < 4; ++ni) {
                const int pix = wn * 64 + ni * 16 + fr;
                const float val = fmaxf(acc[mi][ni][reg] * sc + tt, 0.0f);
                outp[(size_t)(b * CH + o) * HWSZ + (h0 + (pix >> 6)) * WW + (pix & 63)] = val;
            }
        }
    }
}

// ---------------------------------------------------------------------------
extern "C" void kernel_launch(void* const* d_in, const int* in_sizes, int n_in,
                              void* d_out, int out_size, void* d_ws, size_t ws_size,
                              hipStream_t stream)
{
    const float* x     = (const float*)d_in[0];
    const float* q1_w  = (const float*)d_in[1];
    const float* q1_b  = (const float*)d_in[2];
    const float* bn1_g = (const float*)d_in[3];
    const float* bn1_b = (const float*)d_in[4];
    const float* bn1_m = (const float*)d_in[5];
    const float* bn1_v = (const float*)d_in[6];
    const float* q2_w  = (const float*)d_in[7];
    const float* q2_b  = (const float*)d_in[8];
    const float* bn2_g = (const float*)d_in[9];
    const float* bn2_b = (const float*)d_in[10];
    const float* bn2_m = (const float*)d_in[11];
    const float* bn2_v = (const float*)d_in[12];
    const float* p1_w  = (const float*)d_in[13];
    const float* p1_b  = (const float*)d_in[14];
    const float* fus_w = (const float*)d_in[15];
    const float* fus_b = (const float*)d_in[16];
    const float* bn3_g = (const float*)d_in[17];
    const float* bn3_b = (const float*)d_in[18];
    const float* bn3_m = (const float*)d_in[19];
    const float* bn3_v = (const float*)d_in[20];
    const float* gamma = (const float*)d_in[21];
    float* outp = (float*)d_out;

    // ---- workspace carve (float units)
    float* ws = (float*)d_ws;
    size_t off = 0;
    float* py2    = ws + off; off += (size_t)BATCH * CH4 * HWSZ;   // 8,388,608
    float* e1pt   = ws + off; off += (size_t)BATCH * CH  * CH2;    // 2,097,152
    float* e2p    = ws + off; off += (size_t)BATCH * CH2 * CH4;    //   524,288
    float* energy = ws + off; off += (size_t)BATCH * CH  * CH4;    // 1,048,576
    float* p1T    = ws + off; off += (size_t)CH2 * CH2;            //    65,536
    ushort* wH    = (ushort*)(ws + off); off += (size_t)9 * CH * CH / 2;  // 1,179,648 floats
    float* s1 = ws + off; off += CH2;
    float* t1 = ws + off; off += CH2;
    float* s2 = ws + off; off += CH4;
    float* t2 = ws + off; off += CH4;
    float* s3 = ws + off; off += CH;
    float* t3 = ws + off; off += CH;
    // overlap region: py1/e1T/e2 die before preH is written
    float* py1 = ws + off;                             // 16,777,216
    float* e1T = py1 + (size_t)BATCH * CH2 * HWSZ;     //  2,097,152
    float* e2  = e1T + (size_t)BATCH * CH  * CH2;      //    524,288
    ushort* preH = (ushort*)py1;                       // 35,684,352 ushorts (fits in the 19.4M-float region)

    const long sHW_C  = (long)CH  * HWSZ;
    const long sHW_C2 = (long)CH2 * HWSZ;
    const long sHW_C4 = (long)CH4 * HWSZ;

    prep_params<<<1, 512, 0, stream>>>(q1_b, bn1_g, bn1_b, bn1_m, bn1_v,
                                       q2_b, bn2_g, bn2_b, bn2_m, bn2_v,
                                       fus_b, bn3_g, bn3_b, bn3_m, bn3_v,
                                       s1, t1, s2, t2, s3, t3);
    transpose_p1<<<CH2, CH2, 0, stream>>>(p1_w, p1T);
    repack_w<<<CH, CH, 0, stream>>>(fus_w, wH);

    // py1 = relu(bn1(q1_w @ x))           [256 x 4096] per batch, K=512
    gemm_ab<0><<<dim3(64, 4, BATCH), 256, 0, stream>>>(
        q1_w, x, py1, CH2, HWSZ, CH, 0, sHW_C, sHW_C2, s1, t1, nullptr, 0, nullptr, nullptr);

    // py2 = relu(bn2(q2_w @ py1))         [128 x 4096] per batch, K=256
    gemm_ab<0><<<dim3(64, 2, BATCH), 256, 0, stream>>>(
        q2_w, py1, py2, CH4, HWSZ, CH2, 0, sHW_C2, sHW_C4, s2, t2, nullptr, 0, nullptr, nullptr);

    // e1T[d,c] = sum_n x[d,n]*py1[c,n]    [512 x 256] per batch, K=4096
    gemm_abT<0><<<dim3(4, 8, BATCH), 256, 0, stream>>>(
        x, py1, e1T, CH, CH2, HWSZ, sHW_C, sHW_C2, (long)CH * CH2, nullptr);

    // e2[c,d] = sum_n py2[c,n]*py1[d,n]   [128 x 256] per batch, K=4096
    gemm_abT<0><<<dim3(4, 2, BATCH), 256, 0, stream>>>(
        py2, py1, e2, CH4, CH2, HWSZ, sHW_C4, sHW_C2, (long)CH4 * CH2, nullptr);

    // e2p[o,c] = sum_d p1_w[o,d]*e2[c,d] + p1_b[o]   [256 x 128], K=256
    gemm_abT<1><<<dim3(2, 4, BATCH), 256, 0, stream>>>(
        p1_w, e2, e2p, CH2, CH4, CH2, 0, (long)CH4 * CH2, (long)CH2 * CH4, p1_b);

    // e1pt[d,o] = sum_c e1T[d,c]*p1T[c,o] + p1_b[o]  [512 x 256], K=256
    gemm_ab<2><<<dim3(4, 8, BATCH), 256, 0, stream>>>(
        e1T, p1T, e1pt, CH, CH2, CH2, (long)CH * CH2, 0, (long)CH * CH2,
        nullptr, p1_b, nullptr, 0, nullptr, nullptr);

    // energy[c,d] = sum_e e1pt[c,e]*e2p[e,d]         [512 x 128], K=256
    gemm_ab<3><<<dim3(2, 8, BATCH), 256, 0, stream>>>(
        e1pt, e2p, energy, CH, CH4, CH2, (long)CH * CH2, (long)CH2 * CH4, (long)CH * CH4,
        nullptr, nullptr, nullptr, 0, nullptr, nullptr);

    // attention in-place
    softmax_rows<<<BATCH * CH, 64, 0, stream>>>(energy);

    // zero padded preH, then preH = fp16(gamma*(att@py2) + x) pixel-major padded
    zero_buf<<<2048, 256, 0, stream>>>((uint4*)preH, (int)((size_t)BATCH * HP * WP * CH * 2 / 16));
    gemm_ab<4><<<dim3(64, 8, BATCH), 256, 0, stream>>>(
        energy, py2, nullptr, CH, HWSZ, CH4, (long)CH * CH4, sHW_C4, 0,
        nullptr, nullptr, x, sHW_C, gamma, preH);

    // out = relu(bn3(conv3x3(pre) + fus_b)) via fp16 MFMA implicit GEMM
    conv3_mfma<<<2048, 256, 0, stream>>>(preH, wH, s3, t3, outp);
}

// Round 3
// 945.840 us; speedup vs baseline: 6.0200x; 1.5460x over previous
//
#include <hip/hip_runtime.h>
#include <math.h>

// Problem constants (B,C,H,W = 16,512,64,64)
#define BATCH 16
#define CH    512
#define CH2   256
#define CH4   128
#define HH    64
#define WW    64
#define HWSZ  4096
#define EPSV  1e-5f
// padded fp16 conv-input layout [b][h'=0..65][w'=0..65][c=0..511]
#define HP 66
#define WP 66

typedef _Float16 f16x8 __attribute__((ext_vector_type(8)));
typedef float    f32x4 __attribute__((ext_vector_type(4)));

#define GLOBAL_AS __attribute__((address_space(1)))
#define LDS_AS    __attribute__((address_space(3)))

__device__ __forceinline__ void gload16(const void* g, void* l) {
    __builtin_amdgcn_global_load_lds((const GLOBAL_AS unsigned int*)g,
                                     (LDS_AS unsigned int*)l, 16, 0, 0);
}

__device__ __forceinline__ ushort f2h(float v) {
    _Float16 h = (_Float16)v;
    return *(ushort*)&h;
}
__device__ __forceinline__ float h2f(ushort u) {
    _Float16 h = *(_Float16*)&u;
    return (float)h;
}

// ---------------------------------------------------------------------------
// prep: fold BN params.  s = g*rsqrt(v+eps);  t = (conv_bias - m)*s + b
// ---------------------------------------------------------------------------
__global__ void prep_params(
    const float* __restrict__ q1_b, const float* __restrict__ g1, const float* __restrict__ b1,
    const float* __restrict__ m1, const float* __restrict__ v1,
    const float* __restrict__ q2_b, const float* __restrict__ g2, const float* __restrict__ b2,
    const float* __restrict__ m2, const float* __restrict__ v2,
    const float* __restrict__ fus_b, const float* __restrict__ g3, const float* __restrict__ b3,
    const float* __restrict__ m3, const float* __restrict__ v3,
    float* __restrict__ s1, float* __restrict__ t1,
    float* __restrict__ s2, float* __restrict__ t2,
    float* __restrict__ s3, float* __restrict__ t3)
{
    int i = threadIdx.x;
    if (i < CH2) { float s = g1[i] * rsqrtf(v1[i] + EPSV); s1[i] = s; t1[i] = (q1_b[i] - m1[i]) * s + b1[i]; }
    if (i < CH4) { float s = g2[i] * rsqrtf(v2[i] + EPSV); s2[i] = s; t2[i] = (q2_b[i] - m2[i]) * s + b2[i]; }
    if (i < CH)  { float s = g3[i] * rsqrtf(v3[i] + EPSV); s3[i] = s; t3[i] = (fus_b[i] - m3[i]) * s + b3[i]; }
}

__global__ void transpose_p1(const float* __restrict__ p1w, float* __restrict__ p1T)
{
    int c = blockIdx.x;      // 256
    int o = threadIdx.x;     // 256
    p1T[c * CH2 + o] = p1w[o * CH2 + c];
}

// fus_w [o][c][3][3] fp32 -> wH [t][o][c] fp16
__global__ void repack_w(const float* __restrict__ fw, ushort* __restrict__ wH)
{
    int o = blockIdx.x;           // 512
    int c = threadIdx.x;          // 512
    const float* src = fw + ((size_t)o * CH + c) * 9;
    #pragma unroll
    for (int t = 0; t < 9; ++t)
        wH[((size_t)t * CH + o) * CH + c] = f2h(src[t]);
}

__global__ void cvt_h(const float* __restrict__ s, ushort* __restrict__ d, int n)
{
    int i = blockIdx.x * blockDim.x + threadIdx.x;
    if (i < n) d[i] = f2h(s[i]);
}

__global__ void zero_buf(uint4* __restrict__ p, int n)
{
    const uint4 z = make_uint4(0u, 0u, 0u, 0u);
    for (int i = blockIdx.x * blockDim.x + threadIdx.x; i < n; i += gridDim.x * blockDim.x)
        p[i] = z;
}

// x fp32 [b][512][4096] -> xHc fp16 same layout + xHp fp16 [b][4096][512]
__global__ __launch_bounds__(256)
void cvt_x(const float* __restrict__ x, ushort* __restrict__ xHc, ushort* __restrict__ xHp)
{
    __shared__ float t[64][68];
    const int b  = blockIdx.z;
    const int c0 = blockIdx.y * 64;
    const int p0 = blockIdx.x * 64;
    const int tid = threadIdx.x;
    const int tx = tid & 15, ty = tid >> 4;

    const float* xb = x + ((size_t)b * CH + c0) * HWSZ + p0;
    #pragma unroll
    for (int it = 0; it < 4; ++it) {
        const int r = ty + it * 16;
        float4 v = *(const float4*)&xb[(size_t)r * HWSZ + tx * 4];
        *(float4*)&t[r][tx * 4] = v;
        ushort4 u = make_ushort4(f2h(v.x), f2h(v.y), f2h(v.z), f2h(v.w));
        *(ushort4*)&xHc[((size_t)b * CH + c0 + r) * HWSZ + p0 + tx * 4] = u;
    }
    __syncthreads();
    #pragma unroll
    for (int it = 0; it < 4; ++it) {
        const int p = ty + it * 16;
        const int c = tx * 4;
        ushort4 u = make_ushort4(f2h(t[c + 0][p]), f2h(t[c + 1][p]),
                                 f2h(t[c + 2][p]), f2h(t[c + 3][p]));
        *(ushort4*)&xHp[((size_t)b * HWSZ + p0 + p) * CH + c0 + c] = u;
    }
}

// ---------------------------------------------------------------------------
// fp16 MFMA GEMM, 128x128 tile, BK=32, 4 waves (2m x 2n), m97 structure.
// D[m][n] = sum_k A[m][k]*B[n][k]  (both operands k-contiguous fp16)
// blockIdx.z = pk*16 + b  (K-split part pk, batch b)
// EPI 0: relu(acc*scale[m]+shift[m]) -> C0=Hc ushort [m][N], C1=Hp ushort [n][ldHp]
// EPI 1: fp32 partial -> (float*)C0 + pk*pStride
// EPI 2: fp16(gamma*acc + xHp) -> preH padded pixel-major (C0)
// ---------------------------------------------------------------------------
template<int EPI>
__global__ __launch_bounds__(256)
void hgemm(const ushort* __restrict__ A, const ushort* __restrict__ B,
           void* __restrict__ C0, void* __restrict__ C1,
           int N, int KP, int ldA, int ldB, int ldHp,
           long sA, long sB, long sC0, long sC1, long pStride,
           const float* __restrict__ scale, const float* __restrict__ shift,
           const ushort* __restrict__ XHp, const float* __restrict__ gamma)
{
    __shared__ alignas(16) ushort As[4096];  // [128 m][32 k]
    __shared__ alignas(16) ushort Bs[4096];  // [128 n][32 k]

    const int b  = blockIdx.z & 15;
    const int pk = blockIdx.z >> 4;
    const int m0 = blockIdx.y * 128;
    const int n0 = blockIdx.x * 128;
    const int kBase = pk * KP;

    const int tid  = threadIdx.x;
    const int lane = tid & 63;
    const int wv   = tid >> 6;
    const int wm   = wv >> 1;
    const int wn   = wv & 1;

    const int cpart = (lane & 3) * 8;
    const int prow  = lane >> 2;
    const int rA0 = wv * 32 + prow;
    const int rA1 = rA0 + 16;

    const ushort* Ag = A + (size_t)b * sA;
    const ushort* Bg = B + (size_t)b * sB;
    const ushort* aSrc0 = Ag + (size_t)(m0 + rA0) * ldA + cpart + kBase;
    const ushort* aSrc1 = Ag + (size_t)(m0 + rA1) * ldA + cpart + kBase;
    const ushort* bSrc0 = Bg + (size_t)(n0 + rA0) * ldB + cpart + kBase;
    const ushort* bSrc1 = Bg + (size_t)(n0 + rA1) * ldB + cpart + kBase;
    ushort* AsW = &As[wv * 1024];
    ushort* BsW = &Bs[wv * 1024];

    const int fr = lane & 15, fg = lane >> 4;
    const int aOff = (wm * 64 + fr) * 32 + fg * 8;
    const int bOff = (wn * 64 + fr) * 32 + fg * 8;

    f32x4 acc[4][4];
    const f32x4 vzero = {0.f, 0.f, 0.f, 0.f};
    #pragma unroll
    for (int i = 0; i < 4; ++i)
        #pragma unroll
        for (int j = 0; j < 4; ++j) acc[i][j] = vzero;

    for (int k0 = 0; k0 < KP; k0 += 32) {
        gload16(aSrc0 + k0, AsW);
        gload16(aSrc1 + k0, AsW + 512);
        gload16(bSrc0 + k0, BsW);
        gload16(bSrc1 + k0, BsW + 512);
        __syncthreads();

        f16x8 aF[4], bF[4];
        #pragma unroll
        for (int mi = 0; mi < 4; ++mi) aF[mi] = *(const f16x8*)&As[aOff + mi * 512];
        #pragma unroll
        for (int ni = 0; ni < 4; ++ni) bF[ni] = *(const f16x8*)&Bs[bOff + ni * 512];
        #pragma unroll
        for (int mi = 0; mi < 4; ++mi)
            #pragma unroll
            for (int ni = 0; ni < 4; ++ni)
                acc[mi][ni] = __builtin_amdgcn_mfma_f32_16x16x32_f16(aF[mi], bF[ni], acc[mi][ni], 0, 0, 0);
        __syncthreads();
    }

    // D row = m0 + wm*64 + mi*16 + fg*4 + reg ; col = n0 + wn*64 + ni*16 + fr
    #pragma unroll
    for (int mi = 0; mi < 4; ++mi) {
        const int mBase = m0 + wm * 64 + mi * 16 + fg * 4;
        #pragma unroll
        for (int ni = 0; ni < 4; ++ni) {
            const int n = n0 + wn * 64 + ni * 16 + fr;
            if constexpr (EPI == 0) {
                ushort us[4];
                #pragma unroll
                for (int reg = 0; reg < 4; ++reg) {
                    const int m = mBase + reg;
                    float v = fmaxf(acc[mi][ni][reg] * scale[m] + shift[m], 0.0f);
                    us[reg] = f2h(v);
                    ((ushort*)C0)[(size_t)b * sC0 + (size_t)m * N + n] = us[reg];
                }
                *(ushort4*)&((ushort*)C1)[(size_t)b * sC1 + (size_t)n * ldHp + mBase] =
                    make_ushort4(us[0], us[1], us[2], us[3]);
            }
            if constexpr (EPI == 1) {
                float* C = (float*)C0 + pk * pStride + (size_t)b * sC0;
                #pragma unroll
                for (int reg = 0; reg < 4; ++reg)
                    C[(size_t)(mBase + reg) * N + n] = acc[mi][ni][reg];
            }
            if constexpr (EPI == 2) {
                const int h = n >> 6, w = n & 63;
                const float g = gamma[0];
                ushort4 xv = *(const ushort4*)&XHp[((size_t)b * HWSZ + n) * CH + mBase];
                ushort4 pk4;
                pk4.x = f2h(g * acc[mi][ni][0] + h2f(xv.x));
                pk4.y = f2h(g * acc[mi][ni][1] + h2f(xv.y));
                pk4.z = f2h(g * acc[mi][ni][2] + h2f(xv.z));
                pk4.w = f2h(g * acc[mi][ni][3] + h2f(xv.w));
                *(ushort4*)&((ushort*)C0)[((size_t)(b * HP + h + 1) * WP + (w + 1)) * CH + mBase] = pk4;
            }
        }
    }
}

__global__ void reduce_parts(float* __restrict__ dst, const float* __restrict__ src,
                             int n4, int parts, long pstride)
{
    for (int i = blockIdx.x * blockDim.x + threadIdx.x; i < n4; i += gridDim.x * blockDim.x) {
        float4 s = ((const float4*)src)[i];
        for (int p = 1; p < parts; ++p) {
            const float4 v = *(const float4*)&src[(size_t)p * pstride + (size_t)i * 4];
            s.x += v.x; s.y += v.y; s.z += v.z; s.w += v.w;
        }
        ((float4*)dst)[i] = s;
    }
}

// ---------------------------------------------------------------------------
// Tiled fp32 GEMM  C[m,n] = epi( sum_k A[m,k]*B[k,n] ) — small projections only
// EPI: 2 = acc + shift[n] ; 3 = acc
// ---------------------------------------------------------------------------
template<int EPI>
__global__ __launch_bounds__(256)
void gemm_ab(const float* __restrict__ A, const float* __restrict__ Bm,
             float* __restrict__ Cm,
             int M, int N, int K,
             long sA, long sB, long sC,
             const float* __restrict__ shift)
{
    __shared__ float As[16][68];
    __shared__ float Bs[16][68];

    const int b   = blockIdx.z;
    const float* Ab = A  + (long)b * sA;
    const float* Bb = Bm + (long)b * sB;

    const int m0 = blockIdx.y * 64;
    const int n0 = blockIdx.x * 64;
    const int tid = threadIdx.x;
    const int tx = tid & 15;
    const int ty = tid >> 4;

    const int a_m = tid >> 2;
    const int a_k = (tid & 3) * 4;
    const int b_k = tid >> 4;
    const int b_n = (tid & 15) * 4;

    float acc[4][4] = {};

    for (int k0 = 0; k0 < K; k0 += 16) {
        float4 av = *(const float4*)&Ab[(long)(m0 + a_m) * K + k0 + a_k];
        float4 bv = *(const float4*)&Bb[(long)(k0 + b_k) * N + n0 + b_n];
        As[a_k + 0][a_m] = av.x;
        As[a_k + 1][a_m] = av.y;
        As[a_k + 2][a_m] = av.z;
        As[a_k + 3][a_m] = av.w;
        *(float4*)&Bs[b_k][b_n] = bv;
        __syncthreads();
        #pragma unroll
        for (int k = 0; k < 16; ++k) {
            float4 a4 = *(const float4*)&As[k][ty * 4];
            float4 b4 = *(const float4*)&Bs[k][tx * 4];
            float ar[4] = {a4.x, a4.y, a4.z, a4.w};
            float br[4] = {b4.x, b4.y, b4.z, b4.w};
            #pragma unroll
            for (int i = 0; i < 4; ++i)
                #pragma unroll
                for (int j = 0; j < 4; ++j)
                    acc[i][j] += ar[i] * br[j];
        }
        __syncthreads();
    }

    float* Cb = Cm + (long)b * sC;
    #pragma unroll
    for (int i = 0; i < 4; ++i) {
        const int m = m0 + ty * 4 + i;
        float v[4];
        #pragma unroll
        for (int j = 0; j < 4; ++j) {
            float val = acc[i][j];
            if constexpr (EPI == 2) { val = val + shift[n0 + tx * 4 + j]; }
            v[j] = val;
        }
        *(float4*)&Cb[(long)m * N + n0 + tx * 4] = make_float4(v[0], v[1], v[2], v[3]);
    }
}

// Tiled fp32 GEMM  C[m,n] = sum_k A[m,k]*B[n,k] + shift[m]
__global__ __launch_bounds__(256)
void gemm_abT(const float* __restrict__ A, const float* __restrict__ Bm,
              float* __restrict__ Cm,
              int M, int N, int K,
              long sA, long sB, long sC,
              const float* __restrict__ shift)
{
    __shared__ float As[16][68];
    __shared__ float Bs[16][68];

    const int b   = blockIdx.z;
    const float* Ab = A  + (long)b * sA;
    const float* Bb = Bm + (long)b * sB;
    float*       Cb = Cm + (long)b * sC;

    const int m0 = blockIdx.y * 64;
    const int n0 = blockIdx.x * 64;
    const int tid = threadIdx.x;
    const int tx = tid & 15;
    const int ty = tid >> 4;

    const int r  = tid >> 2;
    const int kq = (tid & 3) * 4;

    float acc[4][4] = {};

    for (int k0 = 0; k0 < K; k0 += 16) {
        float4 av = *(const float4*)&Ab[(long)(m0 + r) * K + k0 + kq];
        float4 bv = *(const float4*)&Bb[(long)(n0 + r) * K + k0 + kq];
        As[kq + 0][r] = av.x; As[kq + 1][r] = av.y; As[kq + 2][r] = av.z; As[kq + 3][r] = av.w;
        Bs[kq + 0][r] = bv.x; Bs[kq + 1][r] = bv.y; Bs[kq + 2][r] = bv.z; Bs[kq + 3][r] = bv.w;
        __syncthreads();
        #pragma unroll
        for (int k = 0; k < 16; ++k) {
            float4 a4 = *(const float4*)&As[k][ty * 4];
            float4 b4 = *(const float4*)&Bs[k][tx * 4];
            float ar[4] = {a4.x, a4.y, a4.z, a4.w};
            float br[4] = {b4.x, b4.y, b4.z, b4.w};
            #pragma unroll
            for (int i = 0; i < 4; ++i)
                #pragma unroll
                for (int j = 0; j < 4; ++j)
                    acc[i][j] += ar[i] * br[j];
        }
        __syncthreads();
    }

    #pragma unroll
    for (int i = 0; i < 4; ++i) {
        const int m = m0 + ty * 4 + i;
        float v[4];
        #pragma unroll
        for (int j = 0; j < 4; ++j) v[j] = acc[i][j] + shift[m];
        *(float4*)&Cb[(long)m * N + n0 + tx * 4] = make_float4(v[0], v[1], v[2], v[3]);
    }
}

// ---------------------------------------------------------------------------
// softmax over rows of 128 -> fp16 attention
// ---------------------------------------------------------------------------
__global__ void softmax_rows(const float* __restrict__ e, ushort* __restrict__ attH)
{
    const int row  = blockIdx.x;      // B*512
    const int lane = threadIdx.x;     // 64
    const float* p = e + (long)row * CH4;
    float a = p[lane];
    float c = p[lane + 64];
    float mn = fminf(a, c);
    #pragma unroll
    for (int off = 32; off; off >>= 1) mn = fminf(mn, __shfl_xor(mn, off));
    float ea = expf(mn - a);
    float ec = expf(mn - c);
    float s = ea + ec;
    #pragma unroll
    for (int off = 32; off; off >>= 1) s += __shfl_xor(s, off);
    float inv = 1.0f / s;
    attH[(long)row * CH4 + lane]      = f2h(ea * inv);
    attH[(long)row * CH4 + lane + 64] = f2h(ec * inv);
}

// ---------------------------------------------------------------------------
// 3x3 conv + BN + ReLU via fp16 MFMA implicit GEMM (unchanged from round 2)
// ---------------------------------------------------------------------------
__global__ __launch_bounds__(256)
void conv3_mfma(const ushort* __restrict__ preH, const ushort* __restrict__ wH,
                const float* __restrict__ s3, const float* __restrict__ t3,
                float* __restrict__ outp)
{
    __shared__ alignas(16) ushort As[4096];
    __shared__ alignas(16) ushort Bs[4096];

    const int bid = blockIdx.x;
    const int lin = (bid & 7) * 256 + (bid >> 3);
    const int ob  = lin >> 9;
    const int pt  = lin & 511;
    const int b   = pt >> 5;
    const int h0  = (pt & 31) * 2;
    const int o0  = ob * 128;

    const int tid  = threadIdx.x;
    const int lane = tid & 63;
    const int wv   = tid >> 6;
    const int wm   = wv >> 1;
    const int wn   = wv & 1;

    const int cpart = (lane & 3) * 8;
    const int prow  = lane >> 2;
    const int pA0 = wv * 2, pA1 = pA0 + 1;
    const size_t aBase0 = (size_t)(o0 + pA0 * 16 + prow) * CH + cpart;
    const size_t aBase1 = (size_t)(o0 + pA1 * 16 + prow) * CH + cpart;
    const int P0 = pA0 * 16 + prow, P1 = pA1 * 16 + prow;
    const size_t bBase0 = ((size_t)(b * HP + h0 + (P0 >> 6)) * WP + (P0 & 63)) * CH + cpart;
    const size_t bBase1 = ((size_t)(b * HP + h0 + (P1 >> 6)) * WP + (P1 & 63)) * CH + cpart;
    ushort* AsW = &As[(size_t)wv * 1024];
    ushort* BsW = &Bs[(size_t)wv * 1024];

    const int fr = lane & 15, fg = lane >> 4;
    const int aOff = (wm * 64 + fr) * 32 + fg * 8;
    const int bOff = (wn * 64 + fr) * 32 + fg * 8;

    f32x4 acc[4][4];
    const f32x4 vzero = {0.f, 0.f, 0.f, 0.f};
    #pragma unroll
    for (int i = 0; i < 4; ++i)
        #pragma unroll
        for (int j = 0; j < 4; ++j) acc[i][j] = vzero;

    for (int t = 0; t < 9; ++t) {
        const int r = t / 3, s = t - r * 3;
        const size_t tOffA = (size_t)t * CH * CH;
        const size_t tOffB = (size_t)(r * WP + s) * CH;
        for (int c0 = 0; c0 < CH; c0 += 32) {
            gload16(wH   + tOffA + aBase0 + c0, AsW);
            gload16(wH   + tOffA + aBase1 + c0, AsW + 512);
            gload16(preH + tOffB + bBase0 + c0, BsW);
            gload16(preH + tOffB + bBase1 + c0, BsW + 512);
            __syncthreads();

            f16x8 aF[4], bF[4];
            #pragma unroll
            for (int mi = 0; mi < 4; ++mi) aF[mi] = *(const f16x8*)&As[aOff + mi * 512];
            #pragma unroll
            for (int ni = 0; ni < 4; ++ni) bF[ni] = *(const f16x8*)&Bs[bOff + ni * 512];
            #pragma unroll
            for (int mi = 0; mi < 4; ++mi)
                #pragma unroll
                for (int ni = 0; ni < 4; ++ni)
                    acc[mi][ni] = __builtin_amdgcn_mfma_f32_16x16x32_f16(aF[mi], bF[ni], acc[mi][ni], 0, 0, 0);
            __syncthreads();
        }
    }

    #pragma unroll
    for (int mi = 0; mi < 4; ++mi) {
        #pragma unroll
        for (int reg = 0; reg < 4; ++reg) {
            const int o = o0 + wm * 64 + mi * 16 + fg * 4 + reg;
            const float sc = s3[o], tt = t3[o];
            #pragma unroll
            for (int ni = 0; ni < 4; ++ni) {
                const int pix = wn * 64 + ni * 16 + fr;
                const float val = fmaxf(acc[mi][ni][reg] * sc + tt, 0.0f);
                outp[(size_t)(b * CH + o) * HWSZ + (h0 + (pix >> 6)) * WW + (pix & 63)] = val;
            }
        }
    }
}

// ---------------------------------------------------------------------------
extern "C" void kernel_launch(void* const* d_in, const int* in_sizes, int n_in,
                              void* d_out, int out_size, void* d_ws, size_t ws_size,
                              hipStream_t stream)
{
    const float* x     = (const float*)d_in[0];
    const float* q1_w  = (const float*)d_in[1];
    const float* q1_b  = (const float*)d_in[2];
    const float* bn1_g = (const float*)d_in[3];
    const float* bn1_b = (const float*)d_in[4];
    const float* bn1_m = (const float*)d_in[5];
    const float* bn1_v = (const float*)d_in[6];
    const float* q2_w  = (const float*)d_in[7];
    const float* q2_b  = (const float*)d_in[8];
    const float* bn2_g = (const float*)d_in[9];
    const float* bn2_b = (const float*)d_in[10];
    const float* bn2_m = (const float*)d_in[11];
    const float* bn2_v = (const float*)d_in[12];
    const float* p1_w  = (const float*)d_in[13];
    const float* p1_b  = (const float*)d_in[14];
    const float* fus_w = (const float*)d_in[15];
    const float* fus_b = (const float*)d_in[16];
    const float* bn3_g = (const float*)d_in[17];
    const float* bn3_b = (const float*)d_in[18];
    const float* bn3_m = (const float*)d_in[19];
    const float* bn3_v = (const float*)d_in[20];
    const float* gamma = (const float*)d_in[21];
    float* outp = (float*)d_out;

    // ---- workspace carve (float units, all chunks multiple of 4096 floats)
    float* ws = (float*)d_ws;
    size_t off = 0;
    ushort* py2Hp = (ushort*)(ws + off); off += (size_t)BATCH * HWSZ * CH4 / 2;  // 4,194,304
    ushort* attH  = (ushort*)(ws + off); off += (size_t)BATCH * CH * CH4 / 2;    //   524,288
    ushort* wH    = (ushort*)(ws + off); off += (size_t)9 * CH * CH / 2;         // 1,179,648
    ushort* q1_wH = (ushort*)(ws + off); off += (size_t)CH2 * CH / 2;            //    65,536
    ushort* q2_wH = (ushort*)(ws + off); off += (size_t)CH4 * CH2 / 2;           //    16,384
    float* e1T    = ws + off; off += (size_t)BATCH * CH * CH2;                   // 2,097,152
    float* e2     = ws + off; off += (size_t)BATCH * CH4 * CH2;                  //   524,288
    float* e2p    = ws + off; off += (size_t)BATCH * CH2 * CH4;                  //   524,288
    float* p1T    = ws + off; off += (size_t)CH2 * CH2;                          //    65,536
    // e1Tparts (2 parts) — also hosts e1pt + energy after the reduce
    float* e1Tparts = ws + off; off += 2 * (size_t)BATCH * CH * CH2;             // 4,194,304
    float* e1pt   = e1Tparts;                                                    // 2,097,152
    float* energy = e1Tparts + (size_t)BATCH * CH * CH2;                         // 1,048,576
    ushort* xHp   = (ushort*)(ws + off); off += (size_t)BATCH * HWSZ * CH / 2;   // 16,777,216
    // region R: py1Hc + py1Hp + py2Hc, later reused as preH
    float* R = ws + off; off += (size_t)5 * BATCH * HWSZ * CH2 / 2;              // 20,971,520
    ushort* py1Hc = (ushort*)R;
    ushort* py1Hp = py1Hc + (size_t)BATCH * HWSZ * CH2;
    ushort* py2Hc = py1Hp + (size_t)BATCH * HWSZ * CH2;
    ushort* preH  = (ushort*)R;                       // 35,684,352 us <= region
    // xHc region, later reused for e2parts
    float* xHcR = ws + off; off += (size_t)BATCH * HWSZ * CH / 2;                // 16,777,216
    ushort* xHc    = (ushort*)xHcR;
    float* e2parts = xHcR;                                                       // 8*524,288 fits
    float* s1 = ws + off; off += CH2;
    float* t1 = ws + off; off += CH2;
    float* s2 = ws + off; off += CH4;
    float* t2 = ws + off; off += CH4;
    float* s3 = ws + off; off += CH;
    float* t3 = ws + off; off += CH;

    // strides (elements)
    const long sXc  = (long)CH  * HWSZ;        // 2,097,152 us
    const long sXp  = (long)HWSZ * CH;
    const long sP1c = (long)CH2 * HWSZ;        // 1,048,576 us
    const long sP1p = (long)HWSZ * CH2;
    const long sP2c = (long)CH4 * HWSZ;        //   524,288 us
    const long sP2p = (long)HWSZ * CH4;

    // ---- param prep + weight converts
    prep_params<<<1, 512, 0, stream>>>(q1_b, bn1_g, bn1_b, bn1_m, bn1_v,
                                       q2_b, bn2_g, bn2_b, bn2_m, bn2_v,
                                       fus_b, bn3_g, bn3_b, bn3_m, bn3_v,
                                       s1, t1, s2, t2, s3, t3);
    transpose_p1<<<CH2, CH2, 0, stream>>>(p1_w, p1T);
    repack_w<<<CH, CH, 0, stream>>>(fus_w, wH);
    cvt_h<<<(CH2 * CH + 255) / 256, 256, 0, stream>>>(q1_w, q1_wH, CH2 * CH);
    cvt_h<<<(CH4 * CH2 + 255) / 256, 256, 0, stream>>>(q2_w, q2_wH, CH4 * CH2);
    cvt_x<<<dim3(64, 8, BATCH), 256, 0, stream>>>(x, xHc, xHp);

    // py1 = relu(bn1(W1 @ x)) -> py1Hc + py1Hp     M=256 N=4096 K=512
    hgemm<0><<<dim3(32, 2, BATCH), 256, 0, stream>>>(
        q1_wH, xHp, py1Hc, py1Hp, HWSZ, CH, CH, CH, CH2,
        0, sXp, sP1c, sP1p, 0, s1, t1, nullptr, nullptr);

    // py2 = relu(bn2(W2 @ py1)) -> py2Hc + py2Hp   M=128 N=4096 K=256
    hgemm<0><<<dim3(32, 1, BATCH), 256, 0, stream>>>(
        q2_wH, py1Hp, py2Hc, py2Hp, HWSZ, CH2, CH2, CH2, CH4,
        0, sP1p, sP2c, sP2p, 0, s2, t2, nullptr, nullptr);

    // e1T[d,c] = sum_px x[d,px]*py1[c,px]  M=512 N=256 K=4096, 2-way K-split
    hgemm<1><<<dim3(2, 4, 2 * BATCH), 256, 0, stream>>>(
        xHc, py1Hc, e1Tparts, nullptr, CH2, 2048, HWSZ, HWSZ, 0,
        sXc, sP1c, (long)CH * CH2, 0, (long)BATCH * CH * CH2, nullptr, nullptr, nullptr, nullptr);
    reduce_parts<<<1024, 256, 0, stream>>>(e1T, e1Tparts,
        (int)((size_t)BATCH * CH * CH2 / 4), 2, (long)BATCH * CH * CH2);

    // e2[c,d] = sum_px py2[c,px]*py1[d,px]  M=128 N=256 K=4096, 8-way K-split
    hgemm<1><<<dim3(2, 1, 8 * BATCH), 256, 0, stream>>>(
        py2Hc, py1Hc, e2parts, nullptr, CH2, 512, HWSZ, HWSZ, 0,
        sP2c, sP1c, (long)CH4 * CH2, 0, (long)BATCH * CH4 * CH2, nullptr, nullptr, nullptr, nullptr);
    reduce_parts<<<512, 256, 0, stream>>>(e2, e2parts,
        (int)((size_t)BATCH * CH4 * CH2 / 4), 8, (long)BATCH * CH4 * CH2);

    // e2p[o,c] = sum_d p1_w[o,d]*e2[c,d] + p1_b[o]   [256 x 128], K=256 (fp32)
    gemm_abT<<<dim3(2, 4, BATCH), 256, 0, stream>>>(
        p1_w, e2, e2p, CH2, CH4, CH2, 0, (long)CH4 * CH2, (long)CH2 * CH4, p1_b);

    // e1pt[d,o] = sum_c e1T[d,c]*p1T[c,o] + p1_b[o]  [512 x 256], K=256 (fp32)
    gemm_ab<2><<<dim3(4, 8, BATCH), 256, 0, stream>>>(
        e1T, p1T, e1pt, CH, CH2, CH2, (long)CH * CH2, 0, (long)CH * CH2, p1_b);

    // energy[c,d] = sum_e e1pt[c,e]*e2p[e,d]         [512 x 128], K=256 (fp32)
    gemm_ab<3><<<dim3(2, 8, BATCH), 256, 0, stream>>>(
        e1pt, e2p, energy, CH, CH4, CH2, (long)CH * CH2, (long)CH2 * CH4, (long)CH * CH4,
        nullptr);

    // attention (fp32 softmax -> fp16)
    softmax_rows<<<BATCH * CH, 64, 0, stream>>>(energy, attH);

    // preH = fp16(gamma*(att@py2) + x), padded pixel-major
    zero_buf<<<2048, 256, 0, stream>>>((uint4*)preH, (int)((size_t)BATCH * HP * WP * CH * 2 / 16));
    hgemm<2><<<dim3(32, 4, BATCH), 256, 0, stream>>>(
        attH, py2Hp, preH, nullptr, HWSZ, CH4, CH4, CH4, 0,
        (long)CH * CH4, sP2p, 0, 0, 0, nullptr, nullptr, xHp, gamma);

    // out = relu(bn3(conv3x3(pre) + fus_b)) via fp16 MFMA implicit GEMM
    conv3_mfma<<<2048, 256, 0, stream>>>(preH, wH, s3, t3, outp);
}

// Round 5
// 920.998 us; speedup vs baseline: 6.1824x; 1.0270x over previous
//
#include <hip/hip_runtime.h>
#include <math.h>

// Problem constants (B,C,H,W = 16,512,64,64)
#define BATCH 16
#define CH    512
#define CH2   256
#define CH4   128
#define HH    64
#define WW    64
#define HWSZ  4096
#define EPSV  1e-5f
// padded fp16 conv-input layout [b][h'=0..65][w'=0..65][c=0..511]
#define HP 66
#define WP 66

typedef _Float16 f16x8 __attribute__((ext_vector_type(8)));
typedef float    f32x4 __attribute__((ext_vector_type(4)));

#define GLOBAL_AS __attribute__((address_space(1)))
#define LDS_AS    __attribute__((address_space(3)))

__device__ __forceinline__ void gload16(const void* g, void* l) {
    __builtin_amdgcn_global_load_lds((const GLOBAL_AS unsigned int*)g,
                                     (LDS_AS unsigned int*)l, 16, 0, 0);
}

__device__ __forceinline__ ushort f2h(float v) {
    _Float16 h = (_Float16)v;
    return *(ushort*)&h;
}
__device__ __forceinline__ float h2f(ushort u) {
    _Float16 h = *(_Float16*)&u;
    return (float)h;
}

// ---------------------------------------------------------------------------
// prep: fold BN params.  s = g*rsqrt(v+eps);  t = (conv_bias - m)*s + b
// ---------------------------------------------------------------------------
__global__ void prep_params(
    const float* __restrict__ q1_b, const float* __restrict__ g1, const float* __restrict__ b1,
    const float* __restrict__ m1, const float* __restrict__ v1,
    const float* __restrict__ q2_b, const float* __restrict__ g2, const float* __restrict__ b2,
    const float* __restrict__ m2, const float* __restrict__ v2,
    const float* __restrict__ fus_b, const float* __restrict__ g3, const float* __restrict__ b3,
    const float* __restrict__ m3, const float* __restrict__ v3,
    float* __restrict__ s1, float* __restrict__ t1,
    float* __restrict__ s2, float* __restrict__ t2,
    float* __restrict__ s3, float* __restrict__ t3)
{
    int i = threadIdx.x;
    if (i < CH2) { float s = g1[i] * rsqrtf(v1[i] + EPSV); s1[i] = s; t1[i] = (q1_b[i] - m1[i]) * s + b1[i]; }
    if (i < CH4) { float s = g2[i] * rsqrtf(v2[i] + EPSV); s2[i] = s; t2[i] = (q2_b[i] - m2[i]) * s + b2[i]; }
    if (i < CH)  { float s = g3[i] * rsqrtf(v3[i] + EPSV); s3[i] = s; t3[i] = (fus_b[i] - m3[i]) * s + b3[i]; }
}

__global__ void transpose_p1(const float* __restrict__ p1w, float* __restrict__ p1T)
{
    int c = blockIdx.x;      // 256
    int o = threadIdx.x;     // 256
    p1T[c * CH2 + o] = p1w[o * CH2 + c];
}

// fus_w [o][c][3][3] fp32 -> wH [t][o][c] fp16
__global__ void repack_w(const float* __restrict__ fw, ushort* __restrict__ wH)
{
    int o = blockIdx.x;           // 512
    int c = threadIdx.x;          // 512
    const float* src = fw + ((size_t)o * CH + c) * 9;
    #pragma unroll
    for (int t = 0; t < 9; ++t)
        wH[((size_t)t * CH + o) * CH + c] = f2h(src[t]);
}

__global__ void cvt_h(const float* __restrict__ s, ushort* __restrict__ d, int n)
{
    int i = blockIdx.x * blockDim.x + threadIdx.x;
    if (i < n) d[i] = f2h(s[i]);
}

// zero only the border pixels of preH (interior is fully written by hgemm<2>)
// 16 b x 260 border px x 512 ch ; one uint4 (8 ushorts) per thread
__global__ void zero_border(ushort* __restrict__ preH)
{
    int i = blockIdx.x * blockDim.x + threadIdx.x;   // 16*260*64 total
    const int q  = i & 63;
    const int px = (i >> 6) % 260;
    const int b  = i / (260 * 64);
    int hp, wp;
    if (px < 66)       { hp = 0;            wp = px; }
    else if (px < 132) { hp = 65;           wp = px - 66; }
    else if (px < 196) { hp = px - 132 + 1; wp = 0; }
    else               { hp = px - 196 + 1; wp = 65; }
    const uint4 z = make_uint4(0u, 0u, 0u, 0u);
    *(uint4*)&preH[((size_t)(b * HP + hp) * WP + wp) * CH + q * 8] = z;
}

// x fp32 [b][512][4096] -> xHc fp16 same layout + xHp fp16 [b][4096][512]
__global__ __launch_bounds__(256)
void cvt_x(const float* __restrict__ x, ushort* __restrict__ xHc, ushort* __restrict__ xHp)
{
    __shared__ float t[64][68];
    const int b  = blockIdx.z;
    const int c0 = blockIdx.y * 64;
    const int p0 = blockIdx.x * 64;
    const int tid = threadIdx.x;
    const int tx = tid & 15, ty = tid >> 4;

    const float* xb = x + ((size_t)b * CH + c0) * HWSZ + p0;
    #pragma unroll
    for (int it = 0; it < 4; ++it) {
        const int r = ty + it * 16;
        float4 v = *(const float4*)&xb[(size_t)r * HWSZ + tx * 4];
        *(float4*)&t[r][tx * 4] = v;
        ushort4 u = make_ushort4(f2h(v.x), f2h(v.y), f2h(v.z), f2h(v.w));
        *(ushort4*)&xHc[((size_t)b * CH + c0 + r) * HWSZ + p0 + tx * 4] = u;
    }
    __syncthreads();
    #pragma unroll
    for (int it = 0; it < 4; ++it) {
        const int p = ty + it * 16;
        const int c = tx * 4;
        ushort4 u = make_ushort4(f2h(t[c + 0][p]), f2h(t[c + 1][p]),
                                 f2h(t[c + 2][p]), f2h(t[c + 3][p]));
        *(ushort4*)&xHp[((size_t)b * HWSZ + p0 + p) * CH + c0 + c] = u;
    }
}

// ---------------------------------------------------------------------------
// fp16 MFMA GEMM, 128x128 tile, BK=32, 4 waves (2m x 2n), m97 structure.
// D[m][n] = sum_k A[m][k]*B[n][k]  (both operands k-contiguous fp16)
// blockIdx.z = pk*16 + b  (K-split part pk, batch b)
// EPI 0: relu(acc*scale[m]+shift[m]) -> C0=Hc ushort [m][N], C1=Hp ushort [n][ldHp]
// EPI 1: fp32 partial -> (float*)C0 + pk*pStride
// EPI 2: fp16(gamma*acc + xHp) -> preH padded pixel-major (C0)
// ---------------------------------------------------------------------------
template<int EPI>
__global__ __launch_bounds__(256)
void hgemm(const ushort* __restrict__ A, const ushort* __restrict__ B,
           void* __restrict__ C0, void* __restrict__ C1,
           int N, int KP, int ldA, int ldB, int ldHp,
           long sA, long sB, long sC0, long sC1, long pStride,
           const float* __restrict__ scale, const float* __restrict__ shift,
           const ushort* __restrict__ XHp, const float* __restrict__ gamma)
{
    __shared__ alignas(16) ushort As[4096];  // [128 m][32 k]
    __shared__ alignas(16) ushort Bs[4096];  // [128 n][32 k]

    const int b  = blockIdx.z & 15;
    const int pk = blockIdx.z >> 4;
    const int m0 = blockIdx.y * 128;
    const int n0 = blockIdx.x * 128;
    const int kBase = pk * KP;

    const int tid  = threadIdx.x;
    const int lane = tid & 63;
    const int wv   = tid >> 6;
    const int wm   = wv >> 1;
    const int wn   = wv & 1;

    const int cpart = (lane & 3) * 8;
    const int prow  = lane >> 2;
    const int rA0 = wv * 32 + prow;
    const int rA1 = rA0 + 16;

    const ushort* Ag = A + (size_t)b * sA;
    const ushort* Bg = B + (size_t)b * sB;
    const ushort* aSrc0 = Ag + (size_t)(m0 + rA0) * ldA + cpart + kBase;
    const ushort* aSrc1 = Ag + (size_t)(m0 + rA1) * ldA + cpart + kBase;
    const ushort* bSrc0 = Bg + (size_t)(n0 + rA0) * ldB + cpart + kBase;
    const ushort* bSrc1 = Bg + (size_t)(n0 + rA1) * ldB + cpart + kBase;
    ushort* AsW = &As[wv * 1024];
    ushort* BsW = &Bs[wv * 1024];

    const int fr = lane & 15, fg = lane >> 4;
    const int aOff = (wm * 64 + fr) * 32 + fg * 8;
    const int bOff = (wn * 64 + fr) * 32 + fg * 8;

    f32x4 acc[4][4];
    const f32x4 vzero = {0.f, 0.f, 0.f, 0.f};
    #pragma unroll
    for (int i = 0; i < 4; ++i)
        #pragma unroll
        for (int j = 0; j < 4; ++j) acc[i][j] = vzero;

    for (int k0 = 0; k0 < KP; k0 += 32) {
        gload16(aSrc0 + k0, AsW);
        gload16(aSrc1 + k0, AsW + 512);
        gload16(bSrc0 + k0, BsW);
        gload16(bSrc1 + k0, BsW + 512);
        __syncthreads();

        f16x8 aF[4], bF[4];
        #pragma unroll
        for (int mi = 0; mi < 4; ++mi) aF[mi] = *(const f16x8*)&As[aOff + mi * 512];
        #pragma unroll
        for (int ni = 0; ni < 4; ++ni) bF[ni] = *(const f16x8*)&Bs[bOff + ni * 512];
        #pragma unroll
        for (int mi = 0; mi < 4; ++mi)
            #pragma unroll
            for (int ni = 0; ni < 4; ++ni)
                acc[mi][ni] = __builtin_amdgcn_mfma_f32_16x16x32_f16(aF[mi], bF[ni], acc[mi][ni], 0, 0, 0);
        __syncthreads();
    }

    // D row = m0 + wm*64 + mi*16 + fg*4 + reg ; col = n0 + wn*64 + ni*16 + fr
    #pragma unroll
    for (int mi = 0; mi < 4; ++mi) {
        const int mBase = m0 + wm * 64 + mi * 16 + fg * 4;
        #pragma unroll
        for (int ni = 0; ni < 4; ++ni) {
            const int n = n0 + wn * 64 + ni * 16 + fr;
            if constexpr (EPI == 0) {
                ushort us[4];
                #pragma unroll
                for (int reg = 0; reg < 4; ++reg) {
                    const int m = mBase + reg;
                    float v = fmaxf(acc[mi][ni][reg] * scale[m] + shift[m], 0.0f);
                    us[reg] = f2h(v);
                    ((ushort*)C0)[(size_t)b * sC0 + (size_t)m * N + n] = us[reg];
                }
                *(ushort4*)&((ushort*)C1)[(size_t)b * sC1 + (size_t)n * ldHp + mBase] =
                    make_ushort4(us[0], us[1], us[2], us[3]);
            }
            if constexpr (EPI == 1) {
                float* C = (float*)C0 + pk * pStride + (size_t)b * sC0;
                #pragma unroll
                for (int reg = 0; reg < 4; ++reg)
                    C[(size_t)(mBase + reg) * N + n] = acc[mi][ni][reg];
            }
            if constexpr (EPI == 2) {
                const int h = n >> 6, w = n & 63;
                const float g = gamma[0];
                ushort4 xv = *(const ushort4*)&XHp[((size_t)b * HWSZ + n) * CH + mBase];
                ushort4 pk4;
                pk4.x = f2h(g * acc[mi][ni][0] + h2f(xv.x));
                pk4.y = f2h(g * acc[mi][ni][1] + h2f(xv.y));
                pk4.z = f2h(g * acc[mi][ni][2] + h2f(xv.z));
                pk4.w = f2h(g * acc[mi][ni][3] + h2f(xv.w));
                *(ushort4*)&((ushort*)C0)[((size_t)(b * HP + h + 1) * WP + (w + 1)) * CH + mBase] = pk4;
            }
        }
    }
}

__global__ void reduce_parts(float* __restrict__ dst, const float* __restrict__ src,
                             int n4, int parts, long pstride)
{
    for (int i = blockIdx.x * blockDim.x + threadIdx.x; i < n4; i += gridDim.x * blockDim.x) {
        float4 s = ((const float4*)src)[i];
        for (int p = 1; p < parts; ++p) {
            const float4 v = *(const float4*)&src[(size_t)p * pstride + (size_t)i * 4];
            s.x += v.x; s.y += v.y; s.z += v.z; s.w += v.w;
        }
        ((float4*)dst)[i] = s;
    }
}

// ---------------------------------------------------------------------------
// Tiled fp32 GEMM  C[m,n] = epi( sum_k A[m,k]*B[k,n] ) — small projections only
// EPI: 2 = acc + shift[n] ; 3 = acc
// ---------------------------------------------------------------------------
template<int EPI>
__global__ __launch_bounds__(256)
void gemm_ab(const float* __restrict__ A, const float* __restrict__ Bm,
             float* __restrict__ Cm,
             int M, int N, int K,
             long sA, long sB, long sC,
             const float* __restrict__ shift)
{
    __shared__ float As[16][68];
    __shared__ float Bs[16][68];

    const int b   = blockIdx.z;
    const float* Ab = A  + (long)b * sA;
    const float* Bb = Bm + (long)b * sB;

    const int m0 = blockIdx.y * 64;
    const int n0 = blockIdx.x * 64;
    const int tid = threadIdx.x;
    const int tx = tid & 15;
    const int ty = tid >> 4;

    const int a_m = tid >> 2;
    const int a_k = (tid & 3) * 4;
    const int b_k = tid >> 4;
    const int b_n = (tid & 15) * 4;

    float acc[4][4] = {};

    for (int k0 = 0; k0 < K; k0 += 16) {
        float4 av = *(const float4*)&Ab[(long)(m0 + a_m) * K + k0 + a_k];
        float4 bv = *(const float4*)&Bb[(long)(k0 + b_k) * N + n0 + b_n];
        As[a_k + 0][a_m] = av.x;
        As[a_k + 1][a_m] = av.y;
        As[a_k + 2][a_m] = av.z;
        As[a_k + 3][a_m] = av.w;
        *(float4*)&Bs[b_k][b_n] = bv;
        __syncthreads();
        #pragma unroll
        for (int k = 0; k < 16; ++k) {
            float4 a4 = *(const float4*)&As[k][ty * 4];
            float4 b4 = *(const float4*)&Bs[k][tx * 4];
            float ar[4] = {a4.x, a4.y, a4.z, a4.w};
            float br[4] = {b4.x, b4.y, b4.z, b4.w};
            #pragma unroll
            for (int i = 0; i < 4; ++i)
                #pragma unroll
                for (int j = 0; j < 4; ++j)
                    acc[i][j] += ar[i] * br[j];
        }
        __syncthreads();
    }

    float* Cb = Cm + (long)b * sC;
    #pragma unroll
    for (int i = 0; i < 4; ++i) {
        const int m = m0 + ty * 4 + i;
        float v[4];
        #pragma unroll
        for (int j = 0; j < 4; ++j) {
            float val = acc[i][j];
            if constexpr (EPI == 2) { val = val + shift[n0 + tx * 4 + j]; }
            v[j] = val;
        }
        *(float4*)&Cb[(long)m * N + n0 + tx * 4] = make_float4(v[0], v[1], v[2], v[3]);
    }
}

// Tiled fp32 GEMM  C[m,n] = sum_k A[m,k]*B[n,k] + shift[m]
__global__ __launch_bounds__(256)
void gemm_abT(const float* __restrict__ A, const float* __restrict__ Bm,
              float* __restrict__ Cm,
              int M, int N, int K,
              long sA, long sB, long sC,
              const float* __restrict__ shift)
{
    __shared__ float As[16][68];
    __shared__ float Bs[16][68];

    const int b   = blockIdx.z;
    const float* Ab = A  + (long)b * sA;
    const float* Bb = Bm + (long)b * sB;
    float*       Cb = Cm + (long)b * sC;

    const int m0 = blockIdx.y * 64;
    const int n0 = blockIdx.x * 64;
    const int tid = threadIdx.x;
    const int tx = tid & 15;
    const int ty = tid >> 4;

    const int r  = tid >> 2;
    const int kq = (tid & 3) * 4;

    float acc[4][4] = {};

    for (int k0 = 0; k0 < K; k0 += 16) {
        float4 av = *(const float4*)&Ab[(long)(m0 + r) * K + k0 + kq];
        float4 bv = *(const float4*)&Bb[(long)(n0 + r) * K + k0 + kq];
        As[kq + 0][r] = av.x; As[kq + 1][r] = av.y; As[kq + 2][r] = av.z; As[kq + 3][r] = av.w;
        Bs[kq + 0][r] = bv.x; Bs[kq + 1][r] = bv.y; Bs[kq + 2][r] = bv.z; Bs[kq + 3][r] = bv.w;
        __syncthreads();
        #pragma unroll
        for (int k = 0; k < 16; ++k) {
            float4 a4 = *(const float4*)&As[k][ty * 4];
            float4 b4 = *(const float4*)&Bs[k][tx * 4];
            float ar[4] = {a4.x, a4.y, a4.z, a4.w};
            float br[4] = {b4.x, b4.y, b4.z, b4.w};
            #pragma unroll
            for (int i = 0; i < 4; ++i)
                #pragma unroll
                for (int j = 0; j < 4; ++j)
                    acc[i][j] += ar[i] * br[j];
        }
        __syncthreads();
    }

    #pragma unroll
    for (int i = 0; i < 4; ++i) {
        const int m = m0 + ty * 4 + i;
        float v[4];
        #pragma unroll
        for (int j = 0; j < 4; ++j) v[j] = acc[i][j] + shift[m];
        *(float4*)&Cb[(long)m * N + n0 + tx * 4] = make_float4(v[0], v[1], v[2], v[3]);
    }
}

// ---------------------------------------------------------------------------
// softmax over rows of 128 -> fp16 attention
// ---------------------------------------------------------------------------
__global__ void softmax_rows(const float* __restrict__ e, ushort* __restrict__ attH)
{
    const int row  = blockIdx.x;      // B*512
    const int lane = threadIdx.x;     // 64
    const float* p = e + (long)row * CH4;
    float a = p[lane];
    float c = p[lane + 64];
    float mn = fminf(a, c);
    #pragma unroll
    for (int off = 32; off; off >>= 1) mn = fminf(mn, __shfl_xor(mn, off));
    float ea = expf(mn - a);
    float ec = expf(mn - c);
    float s = ea + ec;
    #pragma unroll
    for (int off = 32; off; off >>= 1) s += __shfl_xor(s, off);
    float inv = 1.0f / s;
    attH[(long)row * CH4 + lane]      = f2h(ea * inv);
    attH[(long)row * CH4 + lane + 64] = f2h(ec * inv);
}

// ---------------------------------------------------------------------------
// 3x3 conv + BN + ReLU, patch-reuse direct-conv MFMA.
// Block: 128 o x 128 px (2 output rows).  Per c-chunk (BK=32): stage the
// 4-row x 66-col input patch in LDS ONCE, then 9 taps read it via shifted
// immediate offsets; only the 8 KB weight slice is re-staged per tap.
// LDS: patch 16.9 KB + weights 8 KB.
// ---------------------------------------------------------------------------
__global__ __launch_bounds__(256)
void conv3_direct(const ushort* __restrict__ preH, const ushort* __restrict__ wH,
                  const float* __restrict__ s3, const float* __restrict__ t3,
                  float* __restrict__ outp)
{
    __shared__ alignas(16) ushort Pt[4 * 66 * 32];   // [r'(0..3)][col 0..65][32 c]
    __shared__ alignas(16) ushort Wl[128 * 32];      // [o 0..127][32 c]

    const int bid = blockIdx.x;
    const int lin = (bid & 7) * 256 + (bid >> 3);    // XCD-chunked swizzle
    const int ob  = lin >> 9;          // 0..3
    const int pt  = lin & 511;         // 16 b x 32 row-pairs
    const int b   = pt >> 5;
    const int h0  = (pt & 31) * 2;     // output rows h0, h0+1
    const int o0  = ob * 128;

    const int tid  = threadIdx.x;
    const int lane = tid & 63;
    const int wv   = tid >> 6;
    const int wm   = wv >> 1;
    const int wn   = wv & 1;

    const int cpart = (lane & 3) * 8;
    const int prow  = lane >> 2;       // 0..15

    // weight staging bases (rows wv*32+prow and +16)
    const size_t aBase0 = (size_t)(o0 + wv * 32 + prow) * CH + cpart;
    const size_t aBase1 = aBase0 + (size_t)16 * CH;
    ushort* WlW = &Wl[wv * 1024];

    // patch staging: padded rows h0..h0+3; wave wv covers cols 1+wv*16 .. 16+wv*16
    const size_t pRow0 = ((size_t)(b * HP + h0) * WP + 1) * CH;   // (row h0, col 1)
    const size_t pLane = (size_t)(wv * 16 + prow) * CH + cpart;

    const int fr = lane & 15, fg = lane >> 4;
    const int aOff = (wm * 64 + fr) * 32 + fg * 8;
    // b-frag per-lane base: row (wn + r), col (ni*16 + fr + s)
    const int bLaneOff = (wn * 66 + fr) * 32 + fg * 8;

    f32x4 acc[4][4];
    const f32x4 vzero = {0.f, 0.f, 0.f, 0.f};
    #pragma unroll
    for (int i = 0; i < 4; ++i)
        #pragma unroll
        for (int j = 0; j < 4; ++j) acc[i][j] = vzero;

    for (int c0 = 0; c0 < CH; c0 += 32) {
        // ---- stage input patch (core cols 1..64 via gload_lds, 4 rows)
        #pragma unroll
        for (int rp = 0; rp < 4; ++rp)
            gload16(preH + pRow0 + (size_t)rp * WP * CH + pLane + c0,
                    &Pt[(rp * 66 + 1 + wv * 16) * 32]);
        // ---- edge cols 0 and 65 (reads are in-bounds: preH is padded)
        if (tid < 32) {
            const int e  = tid >> 4;          // 0 -> col 0, 1 -> col 65
            const int rr = (tid >> 2) & 3;
            const int q  = tid & 3;
            const uint4 v = *(const uint4*)&preH[((size_t)(b * HP + h0 + rr) * WP + e * 65) * CH + c0 + q * 8];
            *(uint4*)&Pt[(rr * 66 + e * 65) * 32 + q * 8] = v;
        }

        // ---- 9 taps from the same patch
        #pragma unroll
        for (int t = 0; t < 9; ++t) {
            const int r = t / 3, s = t - (t / 3) * 3;
            gload16(wH + (size_t)t * CH * CH + aBase0 + c0, WlW);
            gload16(wH + (size_t)t * CH * CH + aBase1 + c0, WlW + 512);
            __syncthreads();

            f16x8 aF[4], bF[4];
            #pragma unroll
            for (int mi = 0; mi < 4; ++mi) aF[mi] = *(const f16x8*)&Wl[aOff + mi * 512];
            #pragma unroll
            for (int ni = 0; ni < 4; ++ni)
                bF[ni] = *(const f16x8*)&Pt[bLaneOff + (r * 66 + s + ni * 16) * 32];
            #pragma unroll
            for (int mi = 0; mi < 4; ++mi)
                #pragma unroll
                for (int ni = 0; ni < 4; ++ni)
                    acc[mi][ni] = __builtin_amdgcn_mfma_f32_16x16x32_f16(aF[mi], bF[ni], acc[mi][ni], 0, 0, 0);
            __syncthreads();
        }
    }

    // epilogue: out row(o) = o0+wm*64+mi*16+fg*4+reg ; px = wn*64 + ni*16 + fr
    #pragma unroll
    for (int mi = 0; mi < 4; ++mi) {
        #pragma unroll
        for (int reg = 0; reg < 4; ++reg) {
            const int o = o0 + wm * 64 + mi * 16 + fg * 4 + reg;
            const float sc = s3[o], tt = t3[o];
            #pragma unroll
            for (int ni = 0; ni < 4; ++ni) {
                const int pix = wn * 64 + ni * 16 + fr;
                const float val = fmaxf(acc[mi][ni][reg] * sc + tt, 0.0f);
                outp[(size_t)(b * CH + o) * HWSZ + (h0 + (pix >> 6)) * WW + (pix & 63)] = val;
            }
        }
    }
}

// ---------------------------------------------------------------------------
extern "C" void kernel_launch(void* const* d_in, const int* in_sizes, int n_in,
                              void* d_out, int out_size, void* d_ws, size_t ws_size,
                              hipStream_t stream)
{
    const float* x     = (const float*)d_in[0];
    const float* q1_w  = (const float*)d_in[1];
    const float* q1_b  = (const float*)d_in[2];
    const float* bn1_g = (const float*)d_in[3];
    const float* bn1_b = (const float*)d_in[4];
    const float* bn1_m = (const float*)d_in[5];
    const float* bn1_v = (const float*)d_in[6];
    const float* q2_w  = (const float*)d_in[7];
    const float* q2_b  = (const float*)d_in[8];
    const float* bn2_g = (const float*)d_in[9];
    const float* bn2_b = (const float*)d_in[10];
    const float* bn2_m = (const float*)d_in[11];
    const float* bn2_v = (const float*)d_in[12];
    const float* p1_w  = (const float*)d_in[13];
    const float* p1_b  = (const float*)d_in[14];
    const float* fus_w = (const float*)d_in[15];
    const float* fus_b = (const float*)d_in[16];
    const float* bn3_g = (const float*)d_in[17];
    const float* bn3_b = (const float*)d_in[18];
    const float* bn3_m = (const float*)d_in[19];
    const float* bn3_v = (const float*)d_in[20];
    const float* gamma = (const float*)d_in[21];
    float* outp = (float*)d_out;

    // ---- workspace carve (float units)
    float* ws = (float*)d_ws;
    size_t off = 0;
    ushort* py2Hp = (ushort*)(ws + off); off += (size_t)BATCH * HWSZ * CH4 / 2;  // 4,194,304
    ushort* attH  = (ushort*)(ws + off); off += (size_t)BATCH * CH * CH4 / 2;    //   524,288
    ushort* wH    = (ushort*)(ws + off); off += (size_t)9 * CH * CH / 2;         // 1,179,648
    ushort* q1_wH = (ushort*)(ws + off); off += (size_t)CH2 * CH / 2;            //    65,536
    ushort* q2_wH = (ushort*)(ws + off); off += (size_t)CH4 * CH2 / 2;           //    16,384
    float* e1T    = ws + off; off += (size_t)BATCH * CH * CH2;                   // 2,097,152
    float* e2     = ws + off; off += (size_t)BATCH * CH4 * CH2;                  //   524,288
    float* e2p    = ws + off; off += (size_t)BATCH * CH2 * CH4;                  //   524,288
    float* p1T    = ws + off; off += (size_t)CH2 * CH2;                          //    65,536
    // e1Tparts (2 parts) — also hosts e1pt + energy after the reduce
    float* e1Tparts = ws + off; off += 2 * (size_t)BATCH * CH * CH2;             // 4,194,304
    float* e1pt   = e1Tparts;
    float* energy = e1Tparts + (size_t)BATCH * CH * CH2;
    ushort* xHp   = (ushort*)(ws + off); off += (size_t)BATCH * HWSZ * CH / 2;   // 16,777,216
    // region R: py1Hc + py1Hp + py2Hc, later reused as preH
    float* R = ws + off; off += (size_t)5 * BATCH * HWSZ * CH2 / 2;              // 20,971,520
    ushort* py1Hc = (ushort*)R;
    ushort* py1Hp = py1Hc + (size_t)BATCH * HWSZ * CH2;
    ushort* py2Hc = py1Hp + (size_t)BATCH * HWSZ * CH2;
    ushort* preH  = (ushort*)R;
    // xHc region, later reused for e2parts
    float* xHcR = ws + off; off += (size_t)BATCH * HWSZ * CH / 2;                // 16,777,216
    ushort* xHc    = (ushort*)xHcR;
    float* e2parts = xHcR;
    float* s1 = ws + off; off += CH2;
    float* t1 = ws + off; off += CH2;
    float* s2 = ws + off; off += CH4;
    float* t2 = ws + off; off += CH4;
    float* s3 = ws + off; off += CH;
    float* t3 = ws + off; off += CH;

    // strides (elements)
    const long sXc  = (long)CH  * HWSZ;
    const long sXp  = (long)HWSZ * CH;
    const long sP1c = (long)CH2 * HWSZ;
    const long sP1p = (long)HWSZ * CH2;
    const long sP2c = (long)CH4 * HWSZ;
    const long sP2p = (long)HWSZ * CH4;

    // ---- param prep + weight converts
    prep_params<<<1, 512, 0, stream>>>(q1_b, bn1_g, bn1_b, bn1_m, bn1_v,
                                       q2_b, bn2_g, bn2_b, bn2_m, bn2_v,
                                       fus_b, bn3_g, bn3_b, bn3_m, bn3_v,
                                       s1, t1, s2, t2, s3, t3);
    transpose_p1<<<CH2, CH2, 0, stream>>>(p1_w, p1T);
    repack_w<<<CH, CH, 0, stream>>>(fus_w, wH);
    cvt_h<<<(CH2 * CH + 255) / 256, 256, 0, stream>>>(q1_w, q1_wH, CH2 * CH);
    cvt_h<<<(CH4 * CH2 + 255) / 256, 256, 0, stream>>>(q2_w, q2_wH, CH4 * CH2);
    cvt_x<<<dim3(64, 8, BATCH), 256, 0, stream>>>(x, xHc, xHp);

    // py1 = relu(bn1(W1 @ x)) -> py1Hc + py1Hp     M=256 N=4096 K=512
    hgemm<0><<<dim3(32, 2, BATCH), 256, 0, stream>>>(
        q1_wH, xHp, py1Hc, py1Hp, HWSZ, CH, CH, CH, CH2,
        0, sXp, sP1c, sP1p, 0, s1, t1, nullptr, nullptr);

    // py2 = relu(bn2(W2 @ py1)) -> py2Hc + py2Hp   M=128 N=4096 K=256
    hgemm<0><<<dim3(32, 1, BATCH), 256, 0, stream>>>(
        q2_wH, py1Hp, py2Hc, py2Hp, HWSZ, CH2, CH2, CH2, CH4,
        0, sP1p, sP2c, sP2p, 0, s2, t2, nullptr, nullptr);

    // e1T[d,c] = sum_px x[d,px]*py1[c,px]  M=512 N=256 K=4096, 2-way K-split
    hgemm<1><<<dim3(2, 4, 2 * BATCH), 256, 0, stream>>>(
        xHc, py1Hc, e1Tparts, nullptr, CH2, 2048, HWSZ, HWSZ, 0,
        sXc, sP1c, (long)CH * CH2, 0, (long)BATCH * CH * CH2, nullptr, nullptr, nullptr, nullptr);
    reduce_parts<<<1024, 256, 0, stream>>>(e1T, e1Tparts,
        (int)((size_t)BATCH * CH * CH2 / 4), 2, (long)BATCH * CH * CH2);

    // e2[c,d] = sum_px py2[c,px]*py1[d,px]  M=128 N=256 K=4096, 8-way K-split
    hgemm<1><<<dim3(2, 1, 8 * BATCH), 256, 0, stream>>>(
        py2Hc, py1Hc, e2parts, nullptr, CH2, 512, HWSZ, HWSZ, 0,
        sP2c, sP1c, (long)CH4 * CH2, 0, (long)BATCH * CH4 * CH2, nullptr, nullptr, nullptr, nullptr);
    reduce_parts<<<512, 256, 0, stream>>>(e2, e2parts,
        (int)((size_t)BATCH * CH4 * CH2 / 4), 8, (long)BATCH * CH4 * CH2);

    // e2p[o,c] = sum_d p1_w[o,d]*e2[c,d] + p1_b[o]   [256 x 128], K=256 (fp32)
    gemm_abT<<<dim3(2, 4, BATCH), 256, 0, stream>>>(
        p1_w, e2, e2p, CH2, CH4, CH2, 0, (long)CH4 * CH2, (long)CH2 * CH4, p1_b);

    // e1pt[d,o] = sum_c e1T[d,c]*p1T[c,o] + p1_b[o]  [512 x 256], K=256 (fp32)
    gemm_ab<2><<<dim3(4, 8, BATCH), 256, 0, stream>>>(
        e1T, p1T, e1pt, CH, CH2, CH2, (long)CH * CH2, 0, (long)CH * CH2, p1_b);

    // energy[c,d] = sum_e e1pt[c,e]*e2p[e,d]         [512 x 128], K=256 (fp32)
    gemm_ab<3><<<dim3(2, 8, BATCH), 256, 0, stream>>>(
        e1pt, e2p, energy, CH, CH4, CH2, (long)CH * CH2, (long)CH2 * CH4, (long)CH * CH4,
        nullptr);

    // attention (fp32 softmax -> fp16)
    softmax_rows<<<BATCH * CH, 64, 0, stream>>>(energy, attH);

    // preH = fp16(gamma*(att@py2) + x), padded pixel-major (border zeroed separately)
    zero_border<<<(BATCH * 260 * 64 + 255) / 256, 256, 0, stream>>>(preH);
    hgemm<2><<<dim3(32, 4, BATCH), 256, 0, stream>>>(
        attH, py2Hp, preH, nullptr, HWSZ, CH4, CH4, CH4, 0,
        (long)CH * CH4, sP2p, 0, 0, 0, nullptr, nullptr, xHp, gamma);

    // out = relu(bn3(conv3x3(pre) + fus_b)) via patch-reuse direct-conv MFMA
    conv3_direct<<<2048, 256, 0, stream>>>(preH, wH, s3, t3, outp);
}

// Round 7
// 913.190 us; speedup vs baseline: 6.2352x; 1.0086x over previous
//
#include <hip/hip_runtime.h>
#include <math.h>

// Problem constants (B,C,H,W = 16,512,64,64)
#define BATCH 16
#define CH    512
#define CH2   256
#define CH4   128
#define HH    64
#define WW    64
#define HWSZ  4096
#define EPSV  1e-5f
// padded fp16 conv-input layout [b][h'=0..65][w'=0..65][c=0..511]
#define HP 66
#define WP 66

typedef _Float16 f16x8 __attribute__((ext_vector_type(8)));
typedef float    f32x4 __attribute__((ext_vector_type(4)));

#define GLOBAL_AS __attribute__((address_space(1)))
#define LDS_AS    __attribute__((address_space(3)))

__device__ __forceinline__ void gload16(const void* g, void* l) {
    __builtin_amdgcn_global_load_lds((const GLOBAL_AS unsigned int*)g,
                                     (LDS_AS unsigned int*)l, 16, 0, 0);
}

__device__ __forceinline__ ushort f2h(float v) {
    _Float16 h = (_Float16)v;
    return *(ushort*)&h;
}
__device__ __forceinline__ float h2f(ushort u) {
    _Float16 h = *(_Float16*)&u;
    return (float)h;
}

// ---------------------------------------------------------------------------
// prep: fold BN params.  s = g*rsqrt(v+eps);  t = (conv_bias - m)*s + b
// ---------------------------------------------------------------------------
__global__ void prep_params(
    const float* __restrict__ q1_b, const float* __restrict__ g1, const float* __restrict__ b1,
    const float* __restrict__ m1, const float* __restrict__ v1,
    const float* __restrict__ q2_b, const float* __restrict__ g2, const float* __restrict__ b2,
    const float* __restrict__ m2, const float* __restrict__ v2,
    const float* __restrict__ fus_b, const float* __restrict__ g3, const float* __restrict__ b3,
    const float* __restrict__ m3, const float* __restrict__ v3,
    float* __restrict__ s1, float* __restrict__ t1,
    float* __restrict__ s2, float* __restrict__ t2,
    float* __restrict__ s3, float* __restrict__ t3)
{
    int i = threadIdx.x;
    if (i < CH2) { float s = g1[i] * rsqrtf(v1[i] + EPSV); s1[i] = s; t1[i] = (q1_b[i] - m1[i]) * s + b1[i]; }
    if (i < CH4) { float s = g2[i] * rsqrtf(v2[i] + EPSV); s2[i] = s; t2[i] = (q2_b[i] - m2[i]) * s + b2[i]; }
    if (i < CH)  { float s = g3[i] * rsqrtf(v3[i] + EPSV); s3[i] = s; t3[i] = (fus_b[i] - m3[i]) * s + b3[i]; }
}

__global__ void transpose_p1(const float* __restrict__ p1w, float* __restrict__ p1T)
{
    int c = blockIdx.x;      // 256
    int o = threadIdx.x;     // 256
    p1T[c * CH2 + o] = p1w[o * CH2 + c];
}

// fus_w [o][c][3][3] fp32 -> wH [t][o][c] fp16
__global__ void repack_w(const float* __restrict__ fw, ushort* __restrict__ wH)
{
    int o = blockIdx.x;           // 512
    int c = threadIdx.x;          // 512
    const float* src = fw + ((size_t)o * CH + c) * 9;
    #pragma unroll
    for (int t = 0; t < 9; ++t)
        wH[((size_t)t * CH + o) * CH + c] = f2h(src[t]);
}

__global__ void cvt_h(const float* __restrict__ s, ushort* __restrict__ d, int n)
{
    int i = blockIdx.x * blockDim.x + threadIdx.x;
    if (i < n) d[i] = f2h(s[i]);
}

// zero only the border pixels of preH (interior is fully written by hgemm<2>)
__global__ void zero_border(ushort* __restrict__ preH)
{
    int i = blockIdx.x * blockDim.x + threadIdx.x;   // 16*260*64 total
    const int q  = i & 63;
    const int px = (i >> 6) % 260;
    const int b  = i / (260 * 64);
    int hp, wp;
    if (px < 66)       { hp = 0;            wp = px; }
    else if (px < 132) { hp = 65;           wp = px - 66; }
    else if (px < 196) { hp = px - 132 + 1; wp = 0; }
    else               { hp = px - 196 + 1; wp = 65; }
    const uint4 z = make_uint4(0u, 0u, 0u, 0u);
    *(uint4*)&preH[((size_t)(b * HP + hp) * WP + wp) * CH + q * 8] = z;
}

// x fp32 [b][512][4096] -> xHc fp16 same layout + xHp fp16 [b][4096][512]
__global__ __launch_bounds__(256)
void cvt_x(const float* __restrict__ x, ushort* __restrict__ xHc, ushort* __restrict__ xHp)
{
    __shared__ float t[64][68];
    const int b  = blockIdx.z;
    const int c0 = blockIdx.y * 64;
    const int p0 = blockIdx.x * 64;
    const int tid = threadIdx.x;
    const int tx = tid & 15, ty = tid >> 4;

    const float* xb = x + ((size_t)b * CH + c0) * HWSZ + p0;
    #pragma unroll
    for (int it = 0; it < 4; ++it) {
        const int r = ty + it * 16;
        float4 v = *(const float4*)&xb[(size_t)r * HWSZ + tx * 4];
        *(float4*)&t[r][tx * 4] = v;
        ushort4 u = make_ushort4(f2h(v.x), f2h(v.y), f2h(v.z), f2h(v.w));
        *(ushort4*)&xHc[((size_t)b * CH + c0 + r) * HWSZ + p0 + tx * 4] = u;
    }
    __syncthreads();
    #pragma unroll
    for (int it = 0; it < 4; ++it) {
        const int p = ty + it * 16;
        const int c = tx * 4;
        ushort4 u = make_ushort4(f2h(t[c + 0][p]), f2h(t[c + 1][p]),
                                 f2h(t[c + 2][p]), f2h(t[c + 3][p]));
        *(ushort4*)&xHp[((size_t)b * HWSZ + p0 + p) * CH + c0 + c] = u;
    }
}

// ---------------------------------------------------------------------------
// fp16 MFMA GEMM, 128x128 tile, BK=32, 4 waves (2m x 2n), m97 structure.
// D[m][n] = sum_k A[m][k]*B[n][k]  (both operands k-contiguous fp16)
// blockIdx.z = pk*16 + b  (K-split part pk, batch b)
// EPI 0: relu(acc*scale[m]+shift[m]) -> C0=Hc ushort [m][N], C1=Hp ushort [n][ldHp]
// EPI 1: fp32 partial -> (float*)C0 + pk*pStride
// EPI 2: fp16(gamma*acc + xHp) -> preH padded pixel-major (C0)
// ---------------------------------------------------------------------------
template<int EPI>
__global__ __launch_bounds__(256)
void hgemm(const ushort* __restrict__ A, const ushort* __restrict__ B,
           void* __restrict__ C0, void* __restrict__ C1,
           int N, int KP, int ldA, int ldB, int ldHp,
           long sA, long sB, long sC0, long sC1, long pStride,
           const float* __restrict__ scale, const float* __restrict__ shift,
           const ushort* __restrict__ XHp, const float* __restrict__ gamma)
{
    __shared__ alignas(16) ushort As[4096];  // [128 m][32 k]
    __shared__ alignas(16) ushort Bs[4096];  // [128 n][32 k]

    const int b  = blockIdx.z & 15;
    const int pk = blockIdx.z >> 4;
    const int m0 = blockIdx.y * 128;
    const int n0 = blockIdx.x * 128;
    const int kBase = pk * KP;

    const int tid  = threadIdx.x;
    const int lane = tid & 63;
    const int wv   = tid >> 6;
    const int wm   = wv >> 1;
    const int wn   = wv & 1;

    const int cpart = (lane & 3) * 8;
    const int prow  = lane >> 2;
    const int rA0 = wv * 32 + prow;
    const int rA1 = rA0 + 16;

    const ushort* Ag = A + (size_t)b * sA;
    const ushort* Bg = B + (size_t)b * sB;
    const ushort* aSrc0 = Ag + (size_t)(m0 + rA0) * ldA + cpart + kBase;
    const ushort* aSrc1 = Ag + (size_t)(m0 + rA1) * ldA + cpart + kBase;
    const ushort* bSrc0 = Bg + (size_t)(n0 + rA0) * ldB + cpart + kBase;
    const ushort* bSrc1 = Bg + (size_t)(n0 + rA1) * ldB + cpart + kBase;
    ushort* AsW = &As[wv * 1024];
    ushort* BsW = &Bs[wv * 1024];

    const int fr = lane & 15, fg = lane >> 4;
    const int aOff = (wm * 64 + fr) * 32 + fg * 8;
    const int bOff = (wn * 64 + fr) * 32 + fg * 8;

    f32x4 acc[4][4];
    const f32x4 vzero = {0.f, 0.f, 0.f, 0.f};
    #pragma unroll
    for (int i = 0; i < 4; ++i)
        #pragma unroll
        for (int j = 0; j < 4; ++j) acc[i][j] = vzero;

    for (int k0 = 0; k0 < KP; k0 += 32) {
        gload16(aSrc0 + k0, AsW);
        gload16(aSrc1 + k0, AsW + 512);
        gload16(bSrc0 + k0, BsW);
        gload16(bSrc1 + k0, BsW + 512);
        __syncthreads();

        f16x8 aF[4], bF[4];
        #pragma unroll
        for (int mi = 0; mi < 4; ++mi) aF[mi] = *(const f16x8*)&As[aOff + mi * 512];
        #pragma unroll
        for (int ni = 0; ni < 4; ++ni) bF[ni] = *(const f16x8*)&Bs[bOff + ni * 512];
        #pragma unroll
        for (int mi = 0; mi < 4; ++mi)
            #pragma unroll
            for (int ni = 0; ni < 4; ++ni)
                acc[mi][ni] = __builtin_amdgcn_mfma_f32_16x16x32_f16(aF[mi], bF[ni], acc[mi][ni], 0, 0, 0);
        __syncthreads();
    }

    // D row = m0 + wm*64 + mi*16 + fg*4 + reg ; col = n0 + wn*64 + ni*16 + fr
    #pragma unroll
    for (int mi = 0; mi < 4; ++mi) {
        const int mBase = m0 + wm * 64 + mi * 16 + fg * 4;
        #pragma unroll
        for (int ni = 0; ni < 4; ++ni) {
            const int n = n0 + wn * 64 + ni * 16 + fr;
            if constexpr (EPI == 0) {
                ushort us[4];
                #pragma unroll
                for (int reg = 0; reg < 4; ++reg) {
                    const int m = mBase + reg;
                    float v = fmaxf(acc[mi][ni][reg] * scale[m] + shift[m], 0.0f);
                    us[reg] = f2h(v);
                    ((ushort*)C0)[(size_t)b * sC0 + (size_t)m * N + n] = us[reg];
                }
                *(ushort4*)&((ushort*)C1)[(size_t)b * sC1 + (size_t)n * ldHp + mBase] =
                    make_ushort4(us[0], us[1], us[2], us[3]);
            }
            if constexpr (EPI == 1) {
                float* C = (float*)C0 + pk * pStride + (size_t)b * sC0;
                #pragma unroll
                for (int reg = 0; reg < 4; ++reg)
                    C[(size_t)(mBase + reg) * N + n] = acc[mi][ni][reg];
            }
            if constexpr (EPI == 2) {
                const int h = n >> 6, w = n & 63;
                const float g = gamma[0];
                ushort4 xv = *(const ushort4*)&XHp[((size_t)b * HWSZ + n) * CH + mBase];
                ushort4 pk4;
                pk4.x = f2h(g * acc[mi][ni][0] + h2f(xv.x));
                pk4.y = f2h(g * acc[mi][ni][1] + h2f(xv.y));
                pk4.z = f2h(g * acc[mi][ni][2] + h2f(xv.z));
                pk4.w = f2h(g * acc[mi][ni][3] + h2f(xv.w));
                *(ushort4*)&((ushort*)C0)[((size_t)(b * HP + h + 1) * WP + (w + 1)) * CH + mBase] = pk4;
            }
        }
    }
}

__global__ void reduce_parts(float* __restrict__ dst, const float* __restrict__ src,
                             int n4, int parts, long pstride)
{
    for (int i = blockIdx.x * blockDim.x + threadIdx.x; i < n4; i += gridDim.x * blockDim.x) {
        float4 s = ((const float4*)src)[i];
        for (int p = 1; p < parts; ++p) {
            const float4 v = *(const float4*)&src[(size_t)p * pstride + (size_t)i * 4];
            s.x += v.x; s.y += v.y; s.z += v.z; s.w += v.w;
        }
        ((float4*)dst)[i] = s;
    }
}

// ---------------------------------------------------------------------------
// Tiled fp32 GEMM  C[m,n] = epi( sum_k A[m,k]*B[k,n] ) — small projections only
// EPI: 2 = acc + shift[n] ; 3 = acc
// ---------------------------------------------------------------------------
template<int EPI>
__global__ __launch_bounds__(256)
void gemm_ab(const float* __restrict__ A, const float* __restrict__ Bm,
             float* __restrict__ Cm,
             int M, int N, int K,
             long sA, long sB, long sC,
             const float* __restrict__ shift)
{
    __shared__ float As[16][68];
    __shared__ float Bs[16][68];

    const int b   = blockIdx.z;
    const float* Ab = A  + (long)b * sA;
    const float* Bb = Bm + (long)b * sB;

    const int m0 = blockIdx.y * 64;
    const int n0 = blockIdx.x * 64;
    const int tid = threadIdx.x;
    const int tx = tid & 15;
    const int ty = tid >> 4;

    const int a_m = tid >> 2;
    const int a_k = (tid & 3) * 4;
    const int b_k = tid >> 4;
    const int b_n = (tid & 15) * 4;

    float acc[4][4] = {};

    for (int k0 = 0; k0 < K; k0 += 16) {
        float4 av = *(const float4*)&Ab[(long)(m0 + a_m) * K + k0 + a_k];
        float4 bv = *(const float4*)&Bb[(long)(k0 + b_k) * N + n0 + b_n];
        As[a_k + 0][a_m] = av.x;
        As[a_k + 1][a_m] = av.y;
        As[a_k + 2][a_m] = av.z;
        As[a_k + 3][a_m] = av.w;
        *(float4*)&Bs[b_k][b_n] = bv;
        __syncthreads();
        #pragma unroll
        for (int k = 0; k < 16; ++k) {
            float4 a4 = *(const float4*)&As[k][ty * 4];
            float4 b4 = *(const float4*)&Bs[k][tx * 4];
            float ar[4] = {a4.x, a4.y, a4.z, a4.w};
            float br[4] = {b4.x, b4.y, b4.z, b4.w};
            #pragma unroll
            for (int i = 0; i < 4; ++i)
                #pragma unroll
                for (int j = 0; j < 4; ++j)
                    acc[i][j] += ar[i] * br[j];
        }
        __syncthreads();
    }

    float* Cb = Cm + (long)b * sC;
    #pragma unroll
    for (int i = 0; i < 4; ++i) {
        const int m = m0 + ty * 4 + i;
        float v[4];
        #pragma unroll
        for (int j = 0; j < 4; ++j) {
            float val = acc[i][j];
            if constexpr (EPI == 2) { val = val + shift[n0 + tx * 4 + j]; }
            v[j] = val;
        }
        *(float4*)&Cb[(long)m * N + n0 + tx * 4] = make_float4(v[0], v[1], v[2], v[3]);
    }
}

// Tiled fp32 GEMM  C[m,n] = sum_k A[m,k]*B[n,k] + shift[m]
__global__ __launch_bounds__(256)
void gemm_abT(const float* __restrict__ A, const float* __restrict__ Bm,
              float* __restrict__ Cm,
              int M, int N, int K,
              long sA, long sB, long sC,
              const float* __restrict__ shift)
{
    __shared__ float As[16][68];
    __shared__ float Bs[16][68];

    const int b   = blockIdx.z;
    const float* Ab = A  + (long)b * sA;
    const float* Bb = Bm + (long)b * sB;
    float*       Cb = Cm + (long)b * sC;

    const int m0 = blockIdx.y * 64;
    const int n0 = blockIdx.x * 64;
    const int tid = threadIdx.x;
    const int tx = tid & 15;
    const int ty = tid >> 4;

    const int r  = tid >> 2;
    const int kq = (tid & 3) * 4;

    float acc[4][4] = {};

    for (int k0 = 0; k0 < K; k0 += 16) {
        float4 av = *(const float4*)&Ab[(long)(m0 + r) * K + k0 + kq];
        float4 bv = *(const float4*)&Bb[(long)(n0 + r) * K + k0 + kq];
        As[kq + 0][r] = av.x; As[kq + 1][r] = av.y; As[kq + 2][r] = av.z; As[kq + 3][r] = av.w;
        Bs[kq + 0][r] = bv.x; Bs[kq + 1][r] = bv.y; Bs[kq + 2][r] = bv.z; Bs[kq + 3][r] = bv.w;
        __syncthreads();
        #pragma unroll
        for (int k = 0; k < 16; ++k) {
            float4 a4 = *(const float4*)&As[k][ty * 4];
            float4 b4 = *(const float4*)&Bs[k][tx * 4];
            float ar[4] = {a4.x, a4.y, a4.z, a4.w};
            float br[4] = {b4.x, b4.y, b4.z, b4.w};
            #pragma unroll
            for (int i = 0; i < 4; ++i)
                #pragma unroll
                for (int j = 0; j < 4; ++j)
                    acc[i][j] += ar[i] * br[j];
        }
        __syncthreads();
    }

    #pragma unroll
    for (int i = 0; i < 4; ++i) {
        const int m = m0 + ty * 4 + i;
        float v[4];
        #pragma unroll
        for (int j = 0; j < 4; ++j) v[j] = acc[i][j] + shift[m];
        *(float4*)&Cb[(long)m * N + n0 + tx * 4] = make_float4(v[0], v[1], v[2], v[3]);
    }
}

// ---------------------------------------------------------------------------
// softmax over rows of 128 -> fp16 attention
// ---------------------------------------------------------------------------
__global__ void softmax_rows(const float* __restrict__ e, ushort* __restrict__ attH)
{
    const int row  = blockIdx.x;      // B*512
    const int lane = threadIdx.x;     // 64
    const float* p = e + (long)row * CH4;
    float a = p[lane];
    float c = p[lane + 64];
    float mn = fminf(a, c);
    #pragma unroll
    for (int off = 32; off; off >>= 1) mn = fminf(mn, __shfl_xor(mn, off));
    float ea = expf(mn - a);
    float ec = expf(mn - c);
    float s = ea + ec;
    #pragma unroll
    for (int off = 32; off; off >>= 1) s += __shfl_xor(s, off);
    float inv = 1.0f / s;
    attH[(long)row * CH4 + lane]      = f2h(ea * inv);
    attH[(long)row * CH4 + lane + 64] = f2h(ec * inv);
}

// ---------------------------------------------------------------------------
// 3x3 conv + BN + ReLU, patch-reuse direct-conv MFMA with a counted-vmcnt
// software pipeline (T3/T4): weights double-buffered in LDS, per-tap schedule
//   { issue next-tap weight gloads -> s_waitcnt vmcnt(2) -> s_barrier ->
//     ds_read frags -> setprio(1) 16 MFMA setprio(0) -> s_barrier }
// Weight loads are never drained to vmcnt(0) inside the loop.  Patch is
// single-buffered (restaged per c-chunk after tap 8); the 2 edge columns for
// ALL chunks are pre-staged once into PeAll (8 KB) and copied LDS->LDS.
// LDS: patch 16.9 KB + 2x8 KB weights + 8 KB edges = 41.5 KB -> 3 blocks/CU.
// ---------------------------------------------------------------------------
__global__ __launch_bounds__(256)
void conv3_pipe(const ushort* __restrict__ preH, const ushort* __restrict__ wH,
                const float* __restrict__ s3, const float* __restrict__ t3,
                float* __restrict__ outp)
{
    __shared__ alignas(16) ushort Pt[4 * 66 * 32];   // [r'][col][32 c]  16896 B
    __shared__ alignas(16) ushort Wl[2][4096];       // dbuf [o 128][32 c] 16384 B
    __shared__ alignas(16) ushort PeAll[8 * 512];    // [rr][e][512 ch]    8192 B

    const int bid = blockIdx.x;
    const int lin = (bid & 7) * 256 + (bid >> 3);    // XCD-chunked swizzle
    const int ob  = lin >> 9;          // 0..3
    const int pt  = lin & 511;         // 16 b x 32 row-pairs
    const int b   = pt >> 5;
    const int h0  = (pt & 31) * 2;     // output rows h0, h0+1
    const int o0  = ob * 128;

    const int tid  = threadIdx.x;
    const int lane = tid & 63;
    const int wv   = tid >> 6;
    const int wm   = wv >> 1;
    const int wn   = wv & 1;

    const int cpart = (lane & 3) * 8;
    const int prow  = lane >> 2;       // 0..15

    // weight staging bases (rows wv*32+prow and +16)
    const size_t aBase0 = (size_t)(o0 + wv * 32 + prow) * CH + cpart;
    const size_t aBase1 = aBase0 + (size_t)16 * CH;

    // patch staging: padded rows h0..h0+3; wave wv covers cols 1+wv*16 .. 16+wv*16
    const size_t pRow0 = ((size_t)(b * HP + h0) * WP + 1) * CH;   // (row h0, col 1)
    const size_t pLane = (size_t)(wv * 16 + prow) * CH + cpart;

    const int fr = lane & 15, fg = lane >> 4;
    const int aOff = (wm * 64 + fr) * 32 + fg * 8;
    const int bLaneOff = (wn * 66 + fr) * 32 + fg * 8;

    f32x4 acc[4][4];
    const f32x4 vzero = {0.f, 0.f, 0.f, 0.f};
    #pragma unroll
    for (int i = 0; i < 4; ++i)
        #pragma unroll
        for (int j = 0; j < 4; ++j) acc[i][j] = vzero;

    // ---------------- prologue: chunk 0 patch + all edges + tap0 weights ----
    #pragma unroll
    for (int rp = 0; rp < 4; ++rp)
        gload16(preH + pRow0 + (size_t)rp * WP * CH + pLane,
                &Pt[(rp * 66 + 1 + wv * 16) * 32]);
    #pragma unroll
    for (int k = 0; k < 2; ++k) {
        const int reg = wv * 2 + k;
        const int rr = reg >> 1, e = reg & 1;
        gload16(preH + ((size_t)(b * HP + h0 + rr) * WP + e * 65) * CH + lane * 8,
                &PeAll[reg * 512]);
    }
    gload16(wH + aBase0, &Wl[0][wv * 1024]);
    gload16(wH + aBase1, &Wl[0][wv * 1024 + 512]);
    asm volatile("s_waitcnt vmcnt(0)" ::: "memory");
    __builtin_amdgcn_s_barrier();
    // edge columns for chunk 0 (LDS -> LDS)
    if (tid < 32) {
        const int e = tid >> 4, rr = (tid >> 2) & 3, q = tid & 3;
        *(uint4*)&Pt[(rr * 66 + e * 65) * 32 + q * 8] =
            *(const uint4*)&PeAll[(rr * 2 + e) * 512 + q * 8];
    }
    asm volatile("s_waitcnt lgkmcnt(0)" ::: "memory");
    __builtin_amdgcn_s_barrier();

    // ---------------- main loop ----------------
    for (int cc = 0; cc < 16; ++cc) {
        const int c0 = cc * 32;
        #pragma unroll
        for (int t = 0; t < 9; ++t) {
            const int wp = (cc + t) & 1;
            // stage NEXT tap's weights into the other buffer (in flight across barrier)
            if (t < 8) {
                gload16(wH + (size_t)(t + 1) * CH * CH + aBase0 + c0, &Wl[wp ^ 1][wv * 1024]);
                gload16(wH + (size_t)(t + 1) * CH * CH + aBase1 + c0, &Wl[wp ^ 1][wv * 1024 + 512]);
            } else if (cc < 15) {
                gload16(wH + aBase0 + c0 + 32, &Wl[wp ^ 1][wv * 1024]);
                gload16(wH + aBase1 + c0 + 32, &Wl[wp ^ 1][wv * 1024 + 512]);
            }
            // counted wait: allow the 2 just-issued loads to keep flying
            asm volatile("s_waitcnt vmcnt(2)" ::: "memory");
            if (t == 0)
                asm volatile("s_waitcnt lgkmcnt(0)" ::: "memory");  // edge-copy visibility
            __builtin_amdgcn_s_barrier();

            const int r = t / 3, s = t - (t / 3) * 3;
            f16x8 aF[4], bF[4];
            #pragma unroll
            for (int mi = 0; mi < 4; ++mi) aF[mi] = *(const f16x8*)&Wl[wp][aOff + mi * 512];
            #pragma unroll
            for (int ni = 0; ni < 4; ++ni)
                bF[ni] = *(const f16x8*)&Pt[bLaneOff + (r * 66 + s + ni * 16) * 32];
            __builtin_amdgcn_s_setprio(1);
            #pragma unroll
            for (int mi = 0; mi < 4; ++mi)
                #pragma unroll
                for (int ni = 0; ni < 4; ++ni)
                    acc[mi][ni] = __builtin_amdgcn_mfma_f32_16x16x32_f16(aF[mi], bF[ni], acc[mi][ni], 0, 0, 0);
            __builtin_amdgcn_s_setprio(0);
            __builtin_amdgcn_s_barrier();
        }
        // chunk transition: restage patch core for chunk cc+1 + edge copy
        if (cc < 15) {
            const int c0n = c0 + 32;
            #pragma unroll
            for (int rp = 0; rp < 4; ++rp)
                gload16(preH + pRow0 + (size_t)rp * WP * CH + pLane + c0n,
                        &Pt[(rp * 66 + 1 + wv * 16) * 32]);
            if (tid < 32) {
                const int e = tid >> 4, rr = (tid >> 2) & 3, q = tid & 3;
                *(uint4*)&Pt[(rr * 66 + e * 65) * 32 + q * 8] =
                    *(const uint4*)&PeAll[(rr * 2 + e) * 512 + c0n + q * 8];
            }
        }
    }

    // epilogue: out row(o) = o0+wm*64+mi*16+fg*4+reg ; px = wn*64 + ni*16 + fr
    #pragma unroll
    for (int mi = 0; mi < 4; ++mi) {
        #pragma unroll
        for (int reg = 0; reg < 4; ++reg) {
            const int o = o0 + wm * 64 + mi * 16 + fg * 4 + reg;
            const float sc = s3[o], tt = t3[o];
            #pragma unroll
            for (int ni = 0; ni < 4; ++ni) {
                const int pix = wn * 64 + ni * 16 + fr;
                const float val = fmaxf(acc[mi][ni][reg] * sc + tt, 0.0f);
                outp[(size_t)(b * CH + o) * HWSZ + (h0 + (pix >> 6)) * WW + (pix & 63)] = val;
            }
        }
    }
}

// ---------------------------------------------------------------------------
extern "C" void kernel_launch(void* const* d_in, const int* in_sizes, int n_in,
                              void* d_out, int out_size, void* d_ws, size_t ws_size,
                              hipStream_t stream)
{
    const float* x     = (const float*)d_in[0];
    const float* q1_w  = (const float*)d_in[1];
    const float* q1_b  = (const float*)d_in[2];
    const float* bn1_g = (const float*)d_in[3];
    const float* bn1_b = (const float*)d_in[4];
    const float* bn1_m = (const float*)d_in[5];
    const float* bn1_v = (const float*)d_in[6];
    const float* q2_w  = (const float*)d_in[7];
    const float* q2_b  = (const float*)d_in[8];
    const float* bn2_g = (const float*)d_in[9];
    const float* bn2_b = (const float*)d_in[10];
    const float* bn2_m = (const float*)d_in[11];
    const float* bn2_v = (const float*)d_in[12];
    const float* p1_w  = (const float*)d_in[13];
    const float* p1_b  = (const float*)d_in[14];
    const float* fus_w = (const float*)d_in[15];
    const float* fus_b = (const float*)d_in[16];
    const float* bn3_g = (const float*)d_in[17];
    const float* bn3_b = (const float*)d_in[18];
    const float* bn3_m = (const float*)d_in[19];
    const float* bn3_v = (const float*)d_in[20];
    const float* gamma = (const float*)d_in[21];
    float* outp = (float*)d_out;

    // ---- workspace carve (float units)
    float* ws = (float*)d_ws;
    size_t off = 0;
    ushort* py2Hp = (ushort*)(ws + off); off += (size_t)BATCH * HWSZ * CH4 / 2;  // 4,194,304
    ushort* attH  = (ushort*)(ws + off); off += (size_t)BATCH * CH * CH4 / 2;    //   524,288
    ushort* wH    = (ushort*)(ws + off); off += (size_t)9 * CH * CH / 2;         // 1,179,648
    ushort* q1_wH = (ushort*)(ws + off); off += (size_t)CH2 * CH / 2;            //    65,536
    ushort* q2_wH = (ushort*)(ws + off); off += (size_t)CH4 * CH2 / 2;           //    16,384
    float* e1T    = ws + off; off += (size_t)BATCH * CH * CH2;                   // 2,097,152
    float* e2     = ws + off; off += (size_t)BATCH * CH4 * CH2;                  //   524,288
    float* e2p    = ws + off; off += (size_t)BATCH * CH2 * CH4;                  //   524,288
    float* p1T    = ws + off; off += (size_t)CH2 * CH2;                          //    65,536
    // e1Tparts (2 parts) — also hosts e1pt + energy after the reduce
    float* e1Tparts = ws + off; off += 2 * (size_t)BATCH * CH * CH2;             // 4,194,304
    float* e1pt   = e1Tparts;
    float* energy = e1Tparts + (size_t)BATCH * CH * CH2;
    ushort* xHp   = (ushort*)(ws + off); off += (size_t)BATCH * HWSZ * CH / 2;   // 16,777,216
    // region R: py1Hc + py1Hp + py2Hc, later reused as preH
    float* R = ws + off; off += (size_t)5 * BATCH * HWSZ * CH2 / 2;              // 20,971,520
    ushort* py1Hc = (ushort*)R;
    ushort* py1Hp = py1Hc + (size_t)BATCH * HWSZ * CH2;
    ushort* py2Hc = py1Hp + (size_t)BATCH * HWSZ * CH2;
    ushort* preH  = (ushort*)R;
    // xHc region, later reused for e2parts
    float* xHcR = ws + off; off += (size_t)BATCH * HWSZ * CH / 2;                // 16,777,216
    ushort* xHc    = (ushort*)xHcR;
    float* e2parts = xHcR;
    float* s1 = ws + off; off += CH2;
    float* t1 = ws + off; off += CH2;
    float* s2 = ws + off; off += CH4;
    float* t2 = ws + off; off += CH4;
    float* s3 = ws + off; off += CH;
    float* t3 = ws + off; off += CH;

    // strides (elements)
    const long sXc  = (long)CH  * HWSZ;
    const long sXp  = (long)HWSZ * CH;
    const long sP1c = (long)CH2 * HWSZ;
    const long sP1p = (long)HWSZ * CH2;
    const long sP2c = (long)CH4 * HWSZ;
    const long sP2p = (long)HWSZ * CH4;

    // ---- param prep + weight converts
    prep_params<<<1, 512, 0, stream>>>(q1_b, bn1_g, bn1_b, bn1_m, bn1_v,
                                       q2_b, bn2_g, bn2_b, bn2_m, bn2_v,
                                       fus_b, bn3_g, bn3_b, bn3_m, bn3_v,
                                       s1, t1, s2, t2, s3, t3);
    transpose_p1<<<CH2, CH2, 0, stream>>>(p1_w, p1T);
    repack_w<<<CH, CH, 0, stream>>>(fus_w, wH);
    cvt_h<<<(CH2 * CH + 255) / 256, 256, 0, stream>>>(q1_w, q1_wH, CH2 * CH);
    cvt_h<<<(CH4 * CH2 + 255) / 256, 256, 0, stream>>>(q2_w, q2_wH, CH4 * CH2);
    cvt_x<<<dim3(64, 8, BATCH), 256, 0, stream>>>(x, xHc, xHp);

    // py1 = relu(bn1(W1 @ x)) -> py1Hc + py1Hp     M=256 N=4096 K=512
    hgemm<0><<<dim3(32, 2, BATCH), 256, 0, stream>>>(
        q1_wH, xHp, py1Hc, py1Hp, HWSZ, CH, CH, CH, CH2,
        0, sXp, sP1c, sP1p, 0, s1, t1, nullptr, nullptr);

    // py2 = relu(bn2(W2 @ py1)) -> py2Hc + py2Hp   M=128 N=4096 K=256
    hgemm<0><<<dim3(32, 1, BATCH), 256, 0, stream>>>(
        q2_wH, py1Hp, py2Hc, py2Hp, HWSZ, CH2, CH2, CH2, CH4,
        0, sP1p, sP2c, sP2p, 0, s2, t2, nullptr, nullptr);

    // e1T[d,c] = sum_px x[d,px]*py1[c,px]  M=512 N=256 K=4096, 2-way K-split
    hgemm<1><<<dim3(2, 4, 2 * BATCH), 256, 0, stream>>>(
        xHc, py1Hc, e1Tparts, nullptr, CH2, 2048, HWSZ, HWSZ, 0,
        sXc, sP1c, (long)CH * CH2, 0, (long)BATCH * CH * CH2, nullptr, nullptr, nullptr, nullptr);
    reduce_parts<<<1024, 256, 0, stream>>>(e1T, e1Tparts,
        (int)((size_t)BATCH * CH * CH2 / 4), 2, (long)BATCH * CH * CH2);

    // e2[c,d] = sum_px py2[c,px]*py1[d,px]  M=128 N=256 K=4096, 8-way K-split
    hgemm<1><<<dim3(2, 1, 8 * BATCH), 256, 0, stream>>>(
        py2Hc, py1Hc, e2parts, nullptr, CH2, 512, HWSZ, HWSZ, 0,
        sP2c, sP1c, (long)CH4 * CH2, 0, (long)BATCH * CH4 * CH2, nullptr, nullptr, nullptr, nullptr);
    reduce_parts<<<512, 256, 0, stream>>>(e2, e2parts,
        (int)((size_t)BATCH * CH4 * CH2 / 4), 8, (long)BATCH * CH4 * CH2);

    // e2p[o,c] = sum_d p1_w[o,d]*e2[c,d] + p1_b[o]   [256 x 128], K=256 (fp32)
    gemm_abT<<<dim3(2, 4, BATCH), 256, 0, stream>>>(
        p1_w, e2, e2p, CH2, CH4, CH2, 0, (long)CH4 * CH2, (long)CH2 * CH4, p1_b);

    // e1pt[d,o] = sum_c e1T[d,c]*p1T[c,o] + p1_b[o]  [512 x 256], K=256 (fp32)
    gemm_ab<2><<<dim3(4, 8, BATCH), 256, 0, stream>>>(
        e1T, p1T, e1pt, CH, CH2, CH2, (long)CH * CH2, 0, (long)CH * CH2, p1_b);

    // energy[c,d] = sum_e e1pt[c,e]*e2p[e,d]         [512 x 128], K=256 (fp32)
    gemm_ab<3><<<dim3(2, 8, BATCH), 256, 0, stream>>>(
        e1pt, e2p, energy, CH, CH4, CH2, (long)CH * CH2, (long)CH2 * CH4, (long)CH * CH4,
        nullptr);

    // attention (fp32 softmax -> fp16)
    softmax_rows<<<BATCH * CH, 64, 0, stream>>>(energy, attH);

    // preH = fp16(gamma*(att@py2) + x), padded pixel-major (border zeroed separately)
    zero_border<<<(BATCH * 260 * 64 + 255) / 256, 256, 0, stream>>>(preH);
    hgemm<2><<<dim3(32, 4, BATCH), 256, 0, stream>>>(
        attH, py2Hp, preH, nullptr, HWSZ, CH4, CH4, CH4, 0,
        (long)CH * CH4, sP2p, 0, 0, 0, nullptr, nullptr, xHp, gamma);

    // out = relu(bn3(conv3x3(pre) + fus_b)) via pipelined direct-conv MFMA
    conv3_pipe<<<2048, 256, 0, stream>>>(preH, wH, s3, t3, outp);
}